// Round 11
// baseline (242.155 us; speedup 1.0000x reference)
//
#include <hip/hip_runtime.h>
#include <math.h>

// Problem constants
#define N_CLASS 64
#define N_SUPPORT 5
#define N_QUERY 64
#define D_IN 1024
#define C_CH 128
#define WIN 5
#define D_FEAT 3200            // C*WIN*WIN
#define NS 320                 // N_CLASS*N_SUPPORT
#define NQ 4096                // N_CLASS*N_QUERY
#define M_ROWS 4416            // NS+NQ
#define M_PAD 4480             // 35 * 128 (fp8 gemm M tiles)

#define ZP_SLICE  (N_CLASS * D_FEAT)          // 204800
#define GT_SLICE  (128 * D_FEAT)              // 409600
#define CR_SLICE  (NQ * 128)                  // 524288
#define NKS       10                          // split-K slices
#define LOSS_BLKS (NQ / 4)                    // 1024

// prep kernel block-range partition
#define PREP_X   4480                          // x->fp8 blocks (4480 rows)
#define PREP_WS  800                           // W_share 64x64 tiles (16 x 50)
#define CONV64   2500                          // W_fine 64x64 conversion tiles
#define GEMM8_BLKS (35 * 25)                   // fp8 gemm blocks (row-major, R8 best)

#define WS_SCALE    64.0f                      // W_share fp8 pre-scale (avoids denormals)
#define WS_INVSCALE 0.015625f

// workspace offsets (bytes)
#define WS_XF8      0u          // [4480][1024] fp8        4,587,520
#define WS_WSF8     4718592u    // [3200][1024] fp8        3,276,800
#define WS_ZSB      8126464u    // [4416][3200] bf16      28,262,400
#define WS_WFB      36388864u   // natural  [k][j] bf16   20,480,000
#define WS_WFTB     56868864u   // transposed [j][k] bf16 20,480,000
#define WS_ARENA    77348864u   // fp32 arena             20,971,520
#define WS_UB       98320384u   // [128][3200] bf16          819,200
#define WS_YB       99139584u   // [128][3200] bf16          819,200
#define WS_GT       99958784u   // [128][3200] bf16          819,200
#define WS_WV       100777984u  //                            12,800
#define WS_P2       100790784u
#define WS_CVEC     100791296u
#define WS_UPOOL    100800128u  // [64][128] f32 (own slot: the fused att block
                                // reads it WHILE zp partials overwrite the arena)

// NOTE (round-2): no producer->consumer fusion across blocks in one dispatch --
// the per-block __threadfence() is an L2 writeback on MI355X (-> 60us). Plain
// device-scope atomicAdd WITHOUT a fence is cheap (R6/R10: loss->out atomics,
// bit-identical absmax).
// NOTE (rounds 4-6): bulk-BW work must not share a dispatch with the MFMA
// pipeline; write-segment size dominates conversion throughput.
// NOTE (round-7): LDS is declared in BYTES; check LDS_Block_Size each round.
// NOTE (round-9): XCD-band remap of the fp8 GEMM grid was within noise ->
// reverted to simple row-major (R8, measured best). The 5x FETCH overshoot is
// not on the critical path (inputs L3-resident; prefetch covers the latency).

typedef __bf16 bf16x8 __attribute__((ext_vector_type(8)));
typedef __bf16 bf16x4 __attribute__((ext_vector_type(4)));
typedef float floatx4 __attribute__((ext_vector_type(4)));
typedef __attribute__((address_space(1))) const void* gptr_t;
typedef __attribute__((address_space(3))) void* lptr_t;

__device__ __forceinline__ float waveReduceSum(float v) {
    for (int off = 32; off > 0; off >>= 1) v += __shfl_xor(v, off, 64);
    return v;
}

// ------ prep: x->fp8 | W_share^T->fp8(x64), 64x64 tiles | zero out[0..1].
// ------ Rows with bit1 set get their 8B halves swapped inside each 16B unit
// ------ (half-level bit of the 64B-row octet swizzle p = o ^ ((row>>1)&7);
// ------ the unit-level XOR (row>>2)&3 is applied on the gload source address
// ------ inside the fp8 GEMM).
__global__ __launch_bounds__(256) void prep_kernel(const float* __restrict__ xs,
                                                   const float* __restrict__ xq,
                                                   const float* __restrict__ W_share,
                                                   unsigned char* __restrict__ Xf8,
                                                   unsigned char* __restrict__ Wsf8,
                                                   float* __restrict__ out)
{
    __shared__ float tile[64][65];   // 16,640 B
    const int b = blockIdx.x;
    const int t = threadIdx.x;

    if (b < PREP_X) {
        if (b == 0 && t < 2) out[t] = 0.f;   // loss/acc atomic accumulators
        // x (xs|xq|zero-pad) -> fp8 e4m3 [4480][1024], 4 elems per thread
        const int e = (b * 256 + t) * 4;
        const int row = e >> 10;
        const int col = e & 1023;
        float4 v = make_float4(0.f, 0.f, 0.f, 0.f);
        if (row < NS)          v = *(const float4*)(xs + (size_t)row * D_IN + col);
        else if (row < M_ROWS) v = *(const float4*)(xq + (size_t)(row - NS) * D_IN + col);
        int p = __builtin_amdgcn_cvt_pk_fp8_f32(v.x, v.y, 0, false);
        p     = __builtin_amdgcn_cvt_pk_fp8_f32(v.z, v.w, p, true);
        const int ocol = col ^ (((row >> 1) & 1) << 3);     // half-swap on row bit1
        *(int*)(Xf8 + (size_t)row * D_IN + ocol) = p;
        return;
    }
    // W_share [1024][3200] -> Wsf8 [3200][1024] fp8, scaled x64, half-swapped.
    // 64x64 tile: load rows k0+i (256B segs), store rows n0+i (64B segs).
    const int tx = t & 63;
    const int ty = t >> 6;           // 0..3
    const int tb = b - PREP_X;
    const int n0 = (tb % 50) * 64;
    const int k0 = (tb / 50) * 64;
#pragma unroll
    for (int i = ty; i < 64; i += 4)
        tile[i][tx] = W_share[(size_t)(k0 + i) * D_FEAT + n0 + tx];
    __syncthreads();
#pragma unroll
    for (int i = ty; i < 64; i += 4) {
        const int p = __builtin_amdgcn_cvt_pk_fp8_f32(tile[tx][i] * WS_SCALE, 0.f,
                                                      0, false);
        const int n = n0 + i;
        const int k = (k0 + tx) ^ (((n >> 1) & 1) << 3);    // half-swap on row bit1
        Wsf8[(size_t)n * D_IN + k] = (unsigned char)(p & 0xff);
    }
}

// -------- fp8 MFMA GEMM, 128^2 tile, ONE barrier per 64B K-chunk ------------
// out = relu(A @ Bt^T * 1/64 + bias), A [4480][1024] fp8, Bt [3200][1024] fp8.
// 256 threads = 4 waves (2M x 2N), per-wave output 64x64, acc[4][4].
// LDS: 3 rotating slots x 16 KB = 48 KB -> 3 blocks/CU resident (875 blocks).
// Per chunk u: {vmcnt(4); barrier [publishes u + certifies u-1's reads done];
// 16x ds_read_b64; stage(u+2); lgkmcnt(0); setprio(1); 32 MFMA; setprio(0)}.
// Accumulation order per acc element unchanged -> bit-identical results.
// LDS swizzle: stored octet p = o ^ ((row>>1)&7) -> conflict-free b64 reads;
// realized as source-unit XOR ((row>>2)&3) on gload addr + prep's half-swap.
__global__ __launch_bounds__(256, 3) void gemm_fp8_128(const unsigned char* __restrict__ A,
                                                       const unsigned char* __restrict__ Bt,
                                                       const float* __restrict__ bias,
                                                       __bf16* __restrict__ out_bf)
{
    __shared__ __align__(16) unsigned char smem[49152];

    const int t    = threadIdx.x;
    const int lane = t & 63;
    const int w    = t >> 6;        // 0..3
    const int wm   = w >> 1;
    const int wn   = w & 1;

    const int bx = blockIdx.x % 25;
    const int by = blockIdx.x / 25;
    const int bm = by * 128;
    const int bn = bx * 128;

    const int q    = lane >> 4;     // k-octet group 0..3
    const int r16  = lane & 15;
    const int m3   = (r16 >> 1) & 7;
    const int off0 = (q ^ m3) * 8;  // half-0 swizzled byte offset; half-1: ^32

    const int rowA = (wm * 64 + r16) * 64;    // + mi*1024
    const int rowB = (wn * 64 + r16) * 64;    // + ni*1024

    // staging: thread t covers (row = t>>2 within a 64-row half, 16B unit t&3)
    const int srow  = t >> 2;
    const int sunit = 16 * ((t & 3) ^ ((srow >> 2) & 3));   // source-unit XOR

    const unsigned char* gA = A  + (size_t)(bm + srow) * D_IN + sunit;
    const unsigned char* gB = Bt + (size_t)(bn + srow) * D_IN + sunit;

    auto stage = [&](int uu, int slot) {
        const unsigned char* ga = gA + uu * 64;
        const unsigned char* gb = gB + uu * 64;
        unsigned char* l = smem + slot * 16384 + t * 16;
        __builtin_amdgcn_global_load_lds((gptr_t)ga,           (lptr_t)l,            16, 0, 0);
        __builtin_amdgcn_global_load_lds((gptr_t)(ga + 65536), (lptr_t)(l + 4096),   16, 0, 0);
        __builtin_amdgcn_global_load_lds((gptr_t)gb,           (lptr_t)(l + 8192),   16, 0, 0);
        __builtin_amdgcn_global_load_lds((gptr_t)(gb + 65536), (lptr_t)(l + 12288),  16, 0, 0);
    };

    floatx4 acc[4][4] = {};
    long av0[4], bv0[4], av1[4], bv1[4];

    auto ld16 = [&](const unsigned char* sa) {
#pragma unroll
        for (int mi = 0; mi < 4; ++mi)
            av0[mi] = *(const long*)(sa + rowA + mi * 1024 + off0);
#pragma unroll
        for (int ni = 0; ni < 4; ++ni)
            bv0[ni] = *(const long*)(sa + 8192 + rowB + ni * 1024 + off0);
#pragma unroll
        for (int mi = 0; mi < 4; ++mi)
            av1[mi] = *(const long*)(sa + rowA + mi * 1024 + (off0 ^ 32));
#pragma unroll
        for (int ni = 0; ni < 4; ++ni)
            bv1[ni] = *(const long*)(sa + 8192 + rowB + ni * 1024 + (off0 ^ 32));
    };
    auto mfma32 = [&]() {
        __builtin_amdgcn_s_setprio(1);
#pragma unroll
        for (int mi = 0; mi < 4; ++mi)
#pragma unroll
            for (int ni = 0; ni < 4; ++ni)
                acc[mi][ni] = __builtin_amdgcn_mfma_f32_16x16x32_fp8_fp8(
                    av0[mi], bv0[ni], acc[mi][ni], 0, 0, 0);
#pragma unroll
        for (int mi = 0; mi < 4; ++mi)
#pragma unroll
            for (int ni = 0; ni < 4; ++ni)
                acc[mi][ni] = __builtin_amdgcn_mfma_f32_16x16x32_fp8_fp8(
                    av1[mi], bv1[ni], acc[mi][ni], 0, 0, 0);
        __builtin_amdgcn_s_setprio(0);
    };

    // prologue: chunks 0,1 in flight (8 loads/thread)
    stage(0, 0);
    stage(1, 1);

    for (int u = 0; u < 14; ++u) {
        const unsigned char* sa = smem + (u % 3) * 16384;
        asm volatile("s_waitcnt vmcnt(4)" ::: "memory");   // chunk u landed
        __builtin_amdgcn_s_barrier();
        ld16(sa);
        stage(u + 2, (u + 2) % 3);
        asm volatile("s_waitcnt lgkmcnt(0)" ::: "memory");
        mfma32();
    }
    {   // u = 14: chunk 15 still in flight, nothing left to stage
        const unsigned char* sa = smem + (14 % 3) * 16384;
        asm volatile("s_waitcnt vmcnt(4)" ::: "memory");
        __builtin_amdgcn_s_barrier();
        ld16(sa);
        asm volatile("s_waitcnt lgkmcnt(0)" ::: "memory");
        mfma32();
    }
    {   // u = 15: drain
        const unsigned char* sa = smem + (15 % 3) * 16384;
        asm volatile("s_waitcnt vmcnt(0)" ::: "memory");
        __builtin_amdgcn_s_barrier();
        ld16(sa);
        asm volatile("s_waitcnt lgkmcnt(0)" ::: "memory");
        mfma32();
    }

    // ---- epilogue: acc -> bf16 via LDS (XOR-swizzled, conflict-free) ->
    // ---- coalesced 256B-row global stores. LDS tile [128][256B] @ smem[0].
    __syncthreads();                 // all frag reads done before overwrite
    float bcol[4];
#pragma unroll
    for (int ni = 0; ni < 4; ++ni) bcol[ni] = bias[bn + wn * 64 + ni * 16 + r16];
    // addr = row*256 + ((col*2) ^ (q<<5)); row = wm*64+mi*16+q*4+reg,
    // col = wn*64+ni*16+r16  ->  base + mi*4096 + reg*256 + ((ni^q)<<5)
    const int ebase = (wm * 64 + q * 4) * 256 + wn * 128 + r16 * 2;
#pragma unroll
    for (int mi = 0; mi < 4; ++mi)
#pragma unroll
        for (int ni = 0; ni < 4; ++ni) {
            const int cb2 = (ni ^ q) << 5;
#pragma unroll
            for (int reg = 0; reg < 4; ++reg) {
                float v = acc[mi][ni][reg] * WS_INVSCALE + bcol[ni];
                v = fmaxf(v, 0.f);
                *(__bf16*)(smem + ebase + mi * 4096 + reg * 256 + cb2) = (__bf16)v;
            }
        }
    __syncthreads();
#pragma unroll
    for (int ps = 0; ps < 8; ++ps) {
        const int idx  = ps * 256 + t;
        const int row  = idx >> 4;           // 0..127
        const int grow = bm + row;
        if (grow < M_ROWS) {
            const int lb = row * 256 + (((idx & 15) << 4) ^ (((row >> 2) & 3) << 5));
            const int4 d = *(const int4*)(smem + lb);
            *(int4*)((char*)out_bf + ((size_t)grow * D_FEAT + bn + (idx & 15) * 8) * 2) = d;
        }
    }
}

// ------------- bf16 MFMA GEMM: split-K partials or full, double-buffered -----
// K-loop: 2 x 32 KB LDS buffers; per iter {__syncthreads() [waits chunk ki's
// gloads (only outstanding VMEM) + publishes + certifies all reads of the
// other buffer done]; stage chunk ki+1 into other buffer; compute chunk ki}.
// Accumulation order unchanged -> bit-identical.
// colLimit: epilogue skips cols >= colLimit (cr only needs 64 of 128 cols).
// Optional fusion: attUpool != null -> last grid block computes the att
// softmax weight vector (fence-free: wv is only read by the NEXT dispatch).
__global__ __launch_bounds__(256) void gemm_bf16(const __bf16* __restrict__ A,
                                                 const __bf16* __restrict__ Bt,
                                                 const float* __restrict__ bias,
                                                 __bf16* __restrict__ out_bf,
                                                 float* __restrict__ out_f32,
                                                 int N, int strideK, int kIters,
                                                 int Mout, int relu, int sliceStride,
                                                 int nbx, int nby, int colLimit,
                                                 const float* __restrict__ attUpool,
                                                 const float* __restrict__ W_att,
                                                 const float* __restrict__ b_att,
                                                 float* __restrict__ wvec)
{
    __shared__ __align__(16) char smem[65536];   // dbuf d: A s-halves @d*32768+{0,8192},
                                                 //         B s-halves @d*32768+16384+{0,8192}
    const int t = threadIdx.x;

    if (attUpool != nullptr && blockIdx.x == gridDim.x - 1) {
        // ---- fused att block: pooled mean -> matvec (W_att via 16KB LDS
        // ---- quarters) -> softmax -> wvec[3200]. k-order 0..127 preserved.
        float* sW   = (float*)smem;                    // [32][128] quarter
        float* s_pm = (float*)(smem + 16384);
        float* s_at = (float*)(smem + 16384 + 512);
        float* s_dg = (float*)(smem + 16384 + 1024);
        if (t < C_CH) {
            float a = 0.f;
            for (int p = 0; p < N_CLASS; ++p) a += attUpool[(size_t)p * C_CH + t];
            s_pm[t] = a * (1.0f / (N_CLASS * 25));
        }
        __syncthreads();
        float acc = (t < C_CH) ? b_att[t] : 0.f;
#pragma unroll
        for (int qtr = 0; qtr < 4; ++qtr) {
            const float4* src = (const float4*)(W_att + qtr * 32 * C_CH);
            float4* dst = (float4*)sW;
#pragma unroll
            for (int i = 0; i < 4; ++i) dst[i * 256 + t] = src[i * 256 + t];
            __syncthreads();
            if (t < C_CH) {
#pragma unroll
                for (int k = 0; k < 32; ++k)
                    acc += s_pm[qtr * 32 + k] * sW[k * C_CH + t];
            }
            __syncthreads();
        }
        if (t < C_CH) s_at[t] = acc;
        __syncthreads();
        if (t < C_CH) {
            float m = -INFINITY;
            for (int k = 0; k < C_CH; ++k) m = fmaxf(m, s_at[k]);
            float s = 0.f;
            for (int k = 0; k < C_CH; ++k) s += expf(s_at[k] - m);
            s_dg[t] = expf(acc - m) / s * (float)C_CH;
        }
        __syncthreads();
        for (int j = t; j < D_FEAT; j += 256) wvec[j] = s_dg[j / 25];
        return;
    }

    int bx, by, ks;
    {
        const int nbxy = nbx * nby;
        ks = blockIdx.x / nbxy;
        const int b = blockIdx.x - ks * nbxy;
        const int fg = nbx >> 3;
        const int full = fg * 8 * nby;
        if (b < full) {
            const int g = b / (8 * nby);
            const int r = b - g * 8 * nby;
            bx = g * 8 + (r & 7);
            by = r >> 3;
        } else {
            const int rem = nbx - fg * 8;
            const int r = b - full;
            bx = fg * 8 + r % rem;
            by = r / rem;
        }
    }

    const int lane = t & 63;
    const int w    = t >> 6;
    const int wm   = w >> 1;
    const int wn   = w & 1;
    const int bm   = by * 128;
    const int bn   = bx * 128;

    const int q    = lane >> 4;
    const int r16  = lane & 15;
    const int sw   = (r16 >> 1) & 3;
    const int cA   = (q ^ sw) * 8;

    const int srow   = w * 16 + (lane >> 2);
    const int sglob8 = (((lane & 3) ^ ((lane >> 3) & 3))) * 8;

    const int kBase = ks * kIters * 64;
    floatx4 acc[4][4] = {};

    auto stageb = [&](int ki, char* base) {
        const int k0 = kBase + ki * 64;
#pragma unroll
        for (int s = 0; s < 2; ++s) {
#pragma unroll
            for (int j = 0; j < 2; ++j) {
                const __bf16* ga = A  + (size_t)(bm + j * 64 + srow) * strideK
                                      + k0 + s * 32 + sglob8;
                const __bf16* gb = Bt + (size_t)(bn + j * 64 + srow) * strideK
                                      + k0 + s * 32 + sglob8;
                char* la = base +         s * 8192 + (j * 256 + w * 64) * 16;
                char* lb = base + 16384 + s * 8192 + (j * 256 + w * 64) * 16;
                __builtin_amdgcn_global_load_lds((gptr_t)ga, (lptr_t)la, 16, 0, 0);
                __builtin_amdgcn_global_load_lds((gptr_t)gb, (lptr_t)lb, 16, 0, 0);
            }
        }
    };

    stageb(0, smem);
    for (int ki = 0; ki < kIters; ++ki) {
        char* base = smem + (ki & 1) * 32768;
        __syncthreads();   // waits chunk ki (vmcnt 0) + publishes; WAR-safe for
                           // the other buffer (all its ds_reads preceded this)
        if (ki + 1 < kIters) stageb(ki + 1, smem + ((ki + 1) & 1) * 32768);

#pragma unroll
        for (int s = 0; s < 2; ++s) {
            const __bf16* sAe = (const __bf16*)(base +         s * 8192);
            const __bf16* sBe = (const __bf16*)(base + 16384 + s * 8192);
            bf16x8 av[4], bv[4];
#pragma unroll
            for (int mi = 0; mi < 4; ++mi)
                av[mi] = *(const bf16x8*)(sAe + ((wm * 64 + mi * 16 + r16) * 32 + cA));
#pragma unroll
            for (int ni = 0; ni < 4; ++ni)
                bv[ni] = *(const bf16x8*)(sBe + ((wn * 64 + ni * 16 + r16) * 32 + cA));
#pragma unroll
            for (int mi = 0; mi < 4; ++mi)
#pragma unroll
                for (int ni = 0; ni < 4; ++ni)
                    acc[mi][ni] = __builtin_amdgcn_mfma_f32_16x16x32_bf16(
                        av[mi], bv[ni], acc[mi][ni], 0, 0, 0);
        }
    }

#pragma unroll
    for (int ni = 0; ni < 4; ++ni) {
        const int col = bn + wn * 64 + ni * 16 + r16;
        if (col < colLimit) {
            const float bcol = sliceStride ? 0.f : bias[col];
#pragma unroll
            for (int mi = 0; mi < 4; ++mi) {
#pragma unroll
                for (int reg = 0; reg < 4; ++reg) {
                    const int row = bm + wm * 64 + mi * 16 + q * 4 + reg;
                    if (row < Mout) {
                        if (sliceStride) {
                            out_f32[(size_t)ks * sliceStride + (size_t)row * N + col] =
                                acc[mi][ni][reg];
                        } else {
                            float v = acc[mi][ni][reg] + bcol;
                            if (relu) v = fmaxf(v, 0.f);
                            if (out_f32) out_f32[(size_t)row * N + col] = v;
                            else         out_bf [(size_t)row * N + col] = (__bf16)v;
                        }
                    }
                }
            }
        }
    }
}

// ---- fused dispatch: blocks 0..127 = support means + channel pools;
// ---- blocks 128.. = W_fine f32 -> Wfb + WfTb (bf16), 64x64 tiles:
// ---- 256B read segments, 128B write segments both layouts. LDS 16.64 KB.
__global__ __launch_bounds__(256) void ut_conv_kernel(const __bf16* __restrict__ z_share,
                                                      const float* __restrict__ W_fine,
                                                      __bf16* __restrict__ u,
                                                      float* __restrict__ upool,
                                                      __bf16* __restrict__ Wfb,
                                                      __bf16* __restrict__ WfTb)
{
    __shared__ __align__(16) char smem_u[16640];   // max(64*65*4, D_FEAT*4)
    const int b = blockIdx.x;
    const int t = threadIdx.x;

    if (b >= 128) {
        // W_fine dual-layout conversion: one 64x64 tile
        float (*tile)[65] = (float(*)[65])smem_u;
        const int tb = b - 128;
        const int tx = t & 63;
        const int ty = t >> 6;           // 0..3
        const int n0 = (tb % 50) * 64;
        const int k0 = (tb / 50) * 64;
#pragma unroll
        for (int i = ty; i < 64; i += 4) {
            const float v = W_fine[(size_t)(k0 + i) * D_FEAT + n0 + tx];
            Wfb[(size_t)(k0 + i) * D_FEAT + n0 + tx] = (__bf16)v;   // 128B rows
            tile[i][tx] = v;
        }
        __syncthreads();
#pragma unroll
        for (int i = ty; i < 64; i += 4)
            WfTb[(size_t)(n0 + i) * D_FEAT + k0 + tx] = (__bf16)tile[tx][i];  // 128B
        return;
    }

    float* srow_ = (float*)smem_u;
    const int p = b;                 // 0..127
    if (p >= N_CLASS) {
        for (int k = t; k < D_FEAT; k += 256) u[(size_t)p * D_FEAT + k] = (__bf16)0.f;
        return;
    }
    const __bf16* base = z_share + (size_t)(p * N_SUPPORT) * D_FEAT;
    for (int k = t; k < D_FEAT; k += 256) {
        float s = 0.f;
#pragma unroll
        for (int ss = 0; ss < N_SUPPORT; ++ss) s += (float)base[(size_t)ss * D_FEAT + k];
        s *= (1.0f / N_SUPPORT);
        u[(size_t)p * D_FEAT + k] = (__bf16)s;
        srow_[k] = s;
    }
    __syncthreads();
    if (t < C_CH) {
        float pool = 0.f;
#pragma unroll
        for (int win = 0; win < 25; ++win) pool += srow_[t * 25 + win];
        upool[(size_t)p * C_CH + t] = pool;
    }
}

// ---------------- y = w*(sum zp_part + bf) bf16 [128 pad][3200]; p2; c --------------
__global__ __launch_bounds__(256) void y_kernel(const float* __restrict__ zp_part,
                                                const float* __restrict__ wv,
                                                const float* __restrict__ bf,
                                                __bf16* __restrict__ y,
                                                float* __restrict__ p2,
                                                float* __restrict__ cvec)
{
    __shared__ float s_red2[8];
    const int p = blockIdx.x;        // 0..127
    const int t = threadIdx.x;
    if (p >= N_CLASS) {
        for (int j = t; j < D_FEAT; j += 256) y[(size_t)p * D_FEAT + j] = (__bf16)0.f;
        return;
    }
    float s2 = 0.f, sc = 0.f;
    for (int j = t; j < D_FEAT; j += 256) {
        float zpf = bf[j];
#pragma unroll
        for (int ss = 0; ss < NKS; ++ss)
            zpf += zp_part[(size_t)ss * ZP_SLICE + (size_t)p * D_FEAT + j];
        const float wj = wv[j];
        y[(size_t)p * D_FEAT + j] = (__bf16)(wj * zpf);
        s2 += wj * zpf * zpf;
        sc += bf[j] * wj * zpf;
    }
    s2 = waveReduceSum(s2);
    sc = waveReduceSum(sc);
    const int lane = t & 63, wid = t >> 6;
    if (lane == 0) { s_red2[wid] = s2; s_red2[4 + wid] = sc; }
    __syncthreads();
    if (t == 0) {
        p2[p]   = s_red2[0] + s_red2[1] + s_red2[2] + s_red2[3];
        cvec[p] = s_red2[4] + s_red2[5] + s_red2[6] + s_red2[7];
    }
}

// ---------------- Gt[p][k] bf16 = sum of NKS fp32 slices [128][3200] ----------------
__global__ __launch_bounds__(256) void gtsum_kernel(const float* __restrict__ gp,
                                                    __bf16* __restrict__ Gt)
{
    const int i4 = blockIdx.x * 256 + threadIdx.x;     // over 409600/4
    if (i4 >= GT_SLICE / 4) return;
    float4 s = make_float4(0.f, 0.f, 0.f, 0.f);
#pragma unroll
    for (int ss = 0; ss < NKS; ++ss) {
        const float4 v = *(const float4*)(gp + (size_t)ss * GT_SLICE + i4 * 4);
        s.x += v.x; s.y += v.y; s.z += v.z; s.w += v.w;
    }
    bf16x4 o = { (__bf16)s.x, (__bf16)s.y, (__bf16)s.z, (__bf16)s.w };
    *(bf16x4*)(Gt + (size_t)i4 * 4) = o;
}

// -------- softmax/loss: one wave per query; block partial scaled by 1/NQ and
// -------- atomically added to out[0..1] (zeroed by prep; fence-free device
// -------- atomics; acc partials exact multiples of 2^-12 -> acc sum exact in
// -------- any order; loss reorder jitter ~1e-6. R6 run: absmax identical).
__global__ __launch_bounds__(256) void loss_kernel(const float* __restrict__ cross_part,
                                                   const float* __restrict__ p2,
                                                   const float* __restrict__ cvec,
                                                   float* __restrict__ out)
{
    __shared__ float s_l[4], s_a[4];
    const int t = threadIdx.x;
    const int lane = t & 63, wid = t >> 6;
    const int i = blockIdx.x * 4 + wid;       // query 0..4095
    float cr = 0.f;
#pragma unroll
    for (int ss = 0; ss < NKS; ++ss)
        cr += cross_part[(size_t)ss * CR_SLICE + (size_t)i * 128 + lane];
    const float neg = 2.0f * (cr + cvec[lane]) - p2[lane];   // -(dist) + const/row
    float m = neg;
    for (int off = 32; off > 0; off >>= 1) m = fmaxf(m, __shfl_xor(m, off, 64));
    float e = expf(neg - m);
    float ssum = e;
    for (int off = 32; off > 0; off >>= 1) ssum += __shfl_xor(ssum, off, 64);
    const float lse = m + logf(ssum);
    const int tcls = i >> 6;
    const float negt = __shfl(neg, tcls, 64);
    float v = -neg; int bi = lane;            // argmin dist == argmax neg, first on tie
    for (int off = 32; off > 0; off >>= 1) {
        const float ov = __shfl_xor(v, off, 64);
        const int   oi = __shfl_xor(bi, off, 64);
        if (ov < v || (ov == v && oi < bi)) { v = ov; bi = oi; }
    }
    if (lane == 0) { s_l[wid] = lse - negt; s_a[wid] = (bi == tcls) ? 1.0f : 0.0f; }
    __syncthreads();
    if (t == 0) {
        atomicAdd(&out[0], (s_l[0] + s_l[1] + s_l[2] + s_l[3]) * (1.0f / NQ));
        atomicAdd(&out[1], (s_a[0] + s_a[1] + s_a[2] + s_a[3]) * (1.0f / NQ));
    }
}

extern "C" void kernel_launch(void* const* d_in, const int* in_sizes, int n_in,
                              void* d_out, int out_size, void* d_ws, size_t ws_size,
                              hipStream_t stream)
{
    const float* xs      = (const float*)d_in[0];
    const float* xq      = (const float*)d_in[1];
    const float* W_share = (const float*)d_in[2];
    const float* b_share = (const float*)d_in[3];
    const float* W_att   = (const float*)d_in[4];
    const float* b_att   = (const float*)d_in[5];
    const float* W_fine  = (const float*)d_in[6];
    const float* b_fine  = (const float*)d_in[7];
    float* out = (float*)d_out;

    char* ws = (char*)d_ws;
    unsigned char* Xf8  = (unsigned char*)(ws + WS_XF8);
    unsigned char* Wsf8 = (unsigned char*)(ws + WS_WSF8);
    __bf16* Zsb     = (__bf16*)(ws + WS_ZSB);
    __bf16* Wfb     = (__bf16*)(ws + WS_WFB);
    __bf16* WfTb    = (__bf16*)(ws + WS_WFTB);
    float*  arena   = (float*) (ws + WS_ARENA);
    float*  zp_part = arena;                  // 10*204800*4 =  8,192,000
    float*  gt_part = arena;                  // 10*409600*4 = 16,384,000
    float*  cr_part = arena;                  // 10*524288*4 = 20,971,520
    __bf16* ub      = (__bf16*)(ws + WS_UB);
    __bf16* yb      = (__bf16*)(ws + WS_YB);
    __bf16* Gt      = (__bf16*)(ws + WS_GT);
    float*  wv      = (float*) (ws + WS_WV);
    float*  p2v     = (float*) (ws + WS_P2);
    float*  cvec    = (float*) (ws + WS_CVEC);
    float*  upool   = (float*) (ws + WS_UPOOL);  // own slot (att overlaps zp)

    // prep: x->fp8 | W_share^T->fp8 x64 (64x64 tiles) | zero out[0..1]
    prep_kernel<<<PREP_X + PREP_WS, 256, 0, stream>>>(xs, xq, W_share, Xf8, Wsf8,
                                                      out);

    // z_share = relu((x @ W_share)*1/64 + b_share) [4416][3200] bf16
    // 128^2-tile 3-resident fp8 GEMM, single barrier per K-chunk (R8 mapping)
    gemm_fp8_128<<<GEMM8_BLKS, 256, 0, stream>>>(Xf8, Wsf8, b_share, Zsb);

    // support means + channel pools, fused with W_fine 64x64 conversion
    ut_conv_kernel<<<128 + CONV64, 256, 0, stream>>>(Zsb, W_fine, ub, upool,
                                                     Wfb, WfTb);

    // zp_part[ks][p][j] = partial u @ Wf  (A=u, Bt=WfTb)  M=64, N=3200, K=3200
    // + fused att tail block (grid 251): upool -> matvec -> softmax -> wv
    gemm_bf16<<<25 * NKS + 1, 256, 0, stream>>>(
        ub, WfTb, nullptr, nullptr, zp_part,
        D_FEAT, D_FEAT, 5, N_CLASS, 0, ZP_SLICE, 25, 1, D_FEAT,
        upool, W_att, b_att, wv);

    // y = w*(zp+b_fine), p2, c   (sums the NKS zp partials)
    y_kernel<<<128, 256, 0, stream>>>(zp_part, wv, b_fine, yb, p2v, cvec);

    // gt_part[ks][p][k] = partial y @ Wf^T  (A=yb, Bt=Wfb natural)  M=128, N=3200
    gemm_bf16<<<25 * NKS, 256, 0, stream>>>(
        yb, Wfb, nullptr, nullptr, gt_part,
        D_FEAT, D_FEAT, 5, 128, 0, GT_SLICE, 25, 1, D_FEAT,
        nullptr, nullptr, nullptr, nullptr);

    // Gt bf16 = sum of slices
    gtsum_kernel<<<(GT_SLICE / 4 + 255) / 256, 256, 0, stream>>>(gt_part, Gt);

    // cr_part[ks][i][p] = partial zs_q @ Gt^T  [4096][128]; only cols 0..63
    // are ever read by loss (classes) -> colLimit 64 halves the write
    gemm_bf16<<<32 * NKS, 256, 0, stream>>>(
        Zsb + (size_t)NS * D_FEAT, Gt, nullptr, nullptr, cr_part,
        128, D_FEAT, 5, NQ, 0, CR_SLICE, 1, 32, 64,
        nullptr, nullptr, nullptr, nullptr);

    // per-query log-softmax + loss/acc -> atomic accumulation into out[0..1]
    loss_kernel<<<LOSS_BLKS, 256, 0, stream>>>(cr_part, p2v, cvec, out);
}

// Round 12
// 220.046 us; speedup vs baseline: 1.1005x; 1.1005x over previous
//
#include <hip/hip_runtime.h>
#include <math.h>

// Problem constants
#define N_CLASS 64
#define N_SUPPORT 5
#define N_QUERY 64
#define D_IN 1024
#define C_CH 128
#define WIN 5
#define D_FEAT 3200            // C*WIN*WIN
#define NS 320                 // N_CLASS*N_SUPPORT
#define NQ 4096                // N_CLASS*N_QUERY
#define M_ROWS 4416            // NS+NQ
#define M_PAD 4480             // 35 * 128 (fp8 gemm M tiles)

#define ZP_SLICE  (N_CLASS * D_FEAT)          // 204800
#define GT_SLICE  (128 * D_FEAT)              // 409600
#define CR_SLICE  (NQ * 128)                  // 524288
#define NKS       10                          // split-K slices
#define LOSS_BLKS (NQ / 4)                    // 1024

// prep kernel block-range partition
#define PREP_X   4480                          // x->fp8 blocks (4480 rows)
#define PREP_WS  800                           // W_share 64x64 tiles (16 x 50)
#define CONV64   2500                          // W_fine 64x64 conversion tiles
#define GEMM8_BLKS (35 * 25)                   // fp8 gemm blocks (row-major, R8 best)

#define WS_SCALE    64.0f                      // W_share fp8 pre-scale (avoids denormals)
#define WS_INVSCALE 0.015625f

// workspace offsets (bytes)
#define WS_XF8      0u          // [4480][1024] fp8        4,587,520
#define WS_WSF8     4718592u    // [3200][1024] fp8        3,276,800
#define WS_ZSB      8126464u    // [4416][3200] bf16      28,262,400
#define WS_WFB      36388864u   // natural  [k][j] bf16   20,480,000
#define WS_WFTB     56868864u   // transposed [j][k] bf16 20,480,000
#define WS_ARENA    77348864u   // fp32 arena             20,971,520
#define WS_UB       98320384u   // [128][3200] bf16          819,200
#define WS_YB       99139584u   // [128][3200] bf16          819,200
#define WS_GT       99958784u   // [128][3200] bf16          819,200
#define WS_WV       100777984u  //                            12,800
#define WS_P2       100790784u
#define WS_CVEC     100791296u
#define WS_LPART    100791808u  // 8,192
#define WS_UPOOL    100800128u  // [64][128] f32 (own slot: the fused att block
                                // reads it WHILE zp partials overwrite the arena)

// NOTE (round-2): no producer->consumer fusion across blocks in one dispatch --
// the per-block __threadfence() is an L2 writeback on MI355X (-> 60us).
// NOTE (rounds 4-6): bulk-BW work must not share a dispatch with the MFMA
// pipeline; write-segment size dominates conversion throughput.
// NOTE (round-7): LDS is declared in BYTES; check LDS_Block_Size each round.
// NOTE (round-9): XCD-band remap of the fp8 GEMM grid was within noise ->
// simple row-major (R8, measured best).
// NOTE (round-10): atomicAdd to d_out cost +22us (output buffer is
// fine-grained/host-visible -> atomics take the slow coherent path). Final
// reductions must end with PLAIN STORES to d_out; workspace atomics are fine.

typedef __bf16 bf16x8 __attribute__((ext_vector_type(8)));
typedef __bf16 bf16x4 __attribute__((ext_vector_type(4)));
typedef float floatx4 __attribute__((ext_vector_type(4)));
typedef __attribute__((address_space(1))) const void* gptr_t;
typedef __attribute__((address_space(3))) void* lptr_t;

__device__ __forceinline__ float waveReduceSum(float v) {
    for (int off = 32; off > 0; off >>= 1) v += __shfl_xor(v, off, 64);
    return v;
}

// ------ prep: x->fp8 | W_share^T->fp8(x64), 64x64 tiles. Rows with bit1 set
// ------ get their 8B halves swapped inside each 16B unit (half-level bit of
// ------ the 64B-row octet swizzle p = o ^ ((row>>1)&7); the unit-level XOR
// ------ (row>>2)&3 is applied on the gload source address in the fp8 GEMM).
__global__ __launch_bounds__(256) void prep_kernel(const float* __restrict__ xs,
                                                   const float* __restrict__ xq,
                                                   const float* __restrict__ W_share,
                                                   unsigned char* __restrict__ Xf8,
                                                   unsigned char* __restrict__ Wsf8)
{
    __shared__ float tile[64][65];   // 16,640 B
    const int b = blockIdx.x;
    const int t = threadIdx.x;

    if (b < PREP_X) {
        // x (xs|xq|zero-pad) -> fp8 e4m3 [4480][1024], 4 elems per thread
        const int e = (b * 256 + t) * 4;
        const int row = e >> 10;
        const int col = e & 1023;
        float4 v = make_float4(0.f, 0.f, 0.f, 0.f);
        if (row < NS)          v = *(const float4*)(xs + (size_t)row * D_IN + col);
        else if (row < M_ROWS) v = *(const float4*)(xq + (size_t)(row - NS) * D_IN + col);
        int p = __builtin_amdgcn_cvt_pk_fp8_f32(v.x, v.y, 0, false);
        p     = __builtin_amdgcn_cvt_pk_fp8_f32(v.z, v.w, p, true);
        const int ocol = col ^ (((row >> 1) & 1) << 3);     // half-swap on row bit1
        *(int*)(Xf8 + (size_t)row * D_IN + ocol) = p;
        return;
    }
    // W_share [1024][3200] -> Wsf8 [3200][1024] fp8, scaled x64, half-swapped.
    // 64x64 tile: load rows k0+i (256B segs), store rows n0+i (64B segs).
    const int tx = t & 63;
    const int ty = t >> 6;           // 0..3
    const int tb = b - PREP_X;
    const int n0 = (tb % 50) * 64;
    const int k0 = (tb / 50) * 64;
#pragma unroll
    for (int i = ty; i < 64; i += 4)
        tile[i][tx] = W_share[(size_t)(k0 + i) * D_FEAT + n0 + tx];
    __syncthreads();
#pragma unroll
    for (int i = ty; i < 64; i += 4) {
        const int p = __builtin_amdgcn_cvt_pk_fp8_f32(tile[tx][i] * WS_SCALE, 0.f,
                                                      0, false);
        const int n = n0 + i;
        const int k = (k0 + tx) ^ (((n >> 1) & 1) << 3);    // half-swap on row bit1
        Wsf8[(size_t)n * D_IN + k] = (unsigned char)(p & 0xff);
    }
}

// -------- fp8 MFMA GEMM, 128^2 tile, ONE barrier per 64B K-chunk ------------
// out = relu(A @ Bt^T * 1/64 + bias), A [4480][1024] fp8, Bt [3200][1024] fp8.
// 256 threads = 4 waves (2M x 2N), per-wave output 64x64, acc[4][4].
// LDS: 3 rotating slots x 16 KB = 48 KB -> 3 blocks/CU resident (875 blocks).
// Per chunk u: {vmcnt(4); barrier [publishes u + certifies u-1's reads done];
// 16x ds_read_b64; stage(u+2); lgkmcnt(0); setprio(1); 32 MFMA; setprio(0)}.
// Accumulation order per acc element unchanged -> bit-identical results.
// LDS swizzle: stored octet p = o ^ ((row>>1)&7) -> conflict-free b64 reads;
// realized as source-unit XOR ((row>>2)&3) on gload addr + prep's half-swap.
__global__ __launch_bounds__(256, 3) void gemm_fp8_128(const unsigned char* __restrict__ A,
                                                       const unsigned char* __restrict__ Bt,
                                                       const float* __restrict__ bias,
                                                       __bf16* __restrict__ out_bf)
{
    __shared__ __align__(16) unsigned char smem[49152];

    const int t    = threadIdx.x;
    const int lane = t & 63;
    const int w    = t >> 6;        // 0..3
    const int wm   = w >> 1;
    const int wn   = w & 1;

    const int bx = blockIdx.x % 25;
    const int by = blockIdx.x / 25;
    const int bm = by * 128;
    const int bn = bx * 128;

    const int q    = lane >> 4;     // k-octet group 0..3
    const int r16  = lane & 15;
    const int m3   = (r16 >> 1) & 7;
    const int off0 = (q ^ m3) * 8;  // half-0 swizzled byte offset; half-1: ^32

    const int rowA = (wm * 64 + r16) * 64;    // + mi*1024
    const int rowB = (wn * 64 + r16) * 64;    // + ni*1024

    // staging: thread t covers (row = t>>2 within a 64-row half, 16B unit t&3)
    const int srow  = t >> 2;
    const int sunit = 16 * ((t & 3) ^ ((srow >> 2) & 3));   // source-unit XOR

    const unsigned char* gA = A  + (size_t)(bm + srow) * D_IN + sunit;
    const unsigned char* gB = Bt + (size_t)(bn + srow) * D_IN + sunit;

    auto stage = [&](int uu, int slot) {
        const unsigned char* ga = gA + uu * 64;
        const unsigned char* gb = gB + uu * 64;
        unsigned char* l = smem + slot * 16384 + t * 16;
        __builtin_amdgcn_global_load_lds((gptr_t)ga,           (lptr_t)l,            16, 0, 0);
        __builtin_amdgcn_global_load_lds((gptr_t)(ga + 65536), (lptr_t)(l + 4096),   16, 0, 0);
        __builtin_amdgcn_global_load_lds((gptr_t)gb,           (lptr_t)(l + 8192),   16, 0, 0);
        __builtin_amdgcn_global_load_lds((gptr_t)(gb + 65536), (lptr_t)(l + 12288),  16, 0, 0);
    };

    floatx4 acc[4][4] = {};
    long av0[4], bv0[4], av1[4], bv1[4];

    auto ld16 = [&](const unsigned char* sa) {
#pragma unroll
        for (int mi = 0; mi < 4; ++mi)
            av0[mi] = *(const long*)(sa + rowA + mi * 1024 + off0);
#pragma unroll
        for (int ni = 0; ni < 4; ++ni)
            bv0[ni] = *(const long*)(sa + 8192 + rowB + ni * 1024 + off0);
#pragma unroll
        for (int mi = 0; mi < 4; ++mi)
            av1[mi] = *(const long*)(sa + rowA + mi * 1024 + (off0 ^ 32));
#pragma unroll
        for (int ni = 0; ni < 4; ++ni)
            bv1[ni] = *(const long*)(sa + 8192 + rowB + ni * 1024 + (off0 ^ 32));
    };
    auto mfma32 = [&]() {
        __builtin_amdgcn_s_setprio(1);
#pragma unroll
        for (int mi = 0; mi < 4; ++mi)
#pragma unroll
            for (int ni = 0; ni < 4; ++ni)
                acc[mi][ni] = __builtin_amdgcn_mfma_f32_16x16x32_fp8_fp8(
                    av0[mi], bv0[ni], acc[mi][ni], 0, 0, 0);
#pragma unroll
        for (int mi = 0; mi < 4; ++mi)
#pragma unroll
            for (int ni = 0; ni < 4; ++ni)
                acc[mi][ni] = __builtin_amdgcn_mfma_f32_16x16x32_fp8_fp8(
                    av1[mi], bv1[ni], acc[mi][ni], 0, 0, 0);
        __builtin_amdgcn_s_setprio(0);
    };

    // prologue: chunks 0,1 in flight (8 loads/thread)
    stage(0, 0);
    stage(1, 1);

    for (int u = 0; u < 14; ++u) {
        const unsigned char* sa = smem + (u % 3) * 16384;
        asm volatile("s_waitcnt vmcnt(4)" ::: "memory");   // chunk u landed
        __builtin_amdgcn_s_barrier();
        ld16(sa);
        stage(u + 2, (u + 2) % 3);
        asm volatile("s_waitcnt lgkmcnt(0)" ::: "memory");
        mfma32();
    }
    {   // u = 14: chunk 15 still in flight, nothing left to stage
        const unsigned char* sa = smem + (14 % 3) * 16384;
        asm volatile("s_waitcnt vmcnt(4)" ::: "memory");
        __builtin_amdgcn_s_barrier();
        ld16(sa);
        asm volatile("s_waitcnt lgkmcnt(0)" ::: "memory");
        mfma32();
    }
    {   // u = 15: drain
        const unsigned char* sa = smem + (15 % 3) * 16384;
        asm volatile("s_waitcnt vmcnt(0)" ::: "memory");
        __builtin_amdgcn_s_barrier();
        ld16(sa);
        asm volatile("s_waitcnt lgkmcnt(0)" ::: "memory");
        mfma32();
    }

    // ---- epilogue: acc -> bf16 via LDS (XOR-swizzled, conflict-free) ->
    // ---- coalesced 256B-row global stores. LDS tile [128][256B] @ smem[0].
    __syncthreads();                 // all frag reads done before overwrite
    float bcol[4];
#pragma unroll
    for (int ni = 0; ni < 4; ++ni) bcol[ni] = bias[bn + wn * 64 + ni * 16 + r16];
    // addr = row*256 + ((col*2) ^ (q<<5)); row = wm*64+mi*16+q*4+reg,
    // col = wn*64+ni*16+r16  ->  base + mi*4096 + reg*256 + ((ni^q)<<5)
    const int ebase = (wm * 64 + q * 4) * 256 + wn * 128 + r16 * 2;
#pragma unroll
    for (int mi = 0; mi < 4; ++mi)
#pragma unroll
        for (int ni = 0; ni < 4; ++ni) {
            const int cb2 = (ni ^ q) << 5;
#pragma unroll
            for (int reg = 0; reg < 4; ++reg) {
                float v = acc[mi][ni][reg] * WS_INVSCALE + bcol[ni];
                v = fmaxf(v, 0.f);
                *(__bf16*)(smem + ebase + mi * 4096 + reg * 256 + cb2) = (__bf16)v;
            }
        }
    __syncthreads();
#pragma unroll
    for (int ps = 0; ps < 8; ++ps) {
        const int idx  = ps * 256 + t;
        const int row  = idx >> 4;           // 0..127
        const int grow = bm + row;
        if (grow < M_ROWS) {
            const int lb = row * 256 + (((idx & 15) << 4) ^ (((row >> 2) & 3) << 5));
            const int4 d = *(const int4*)(smem + lb);
            *(int4*)((char*)out_bf + ((size_t)grow * D_FEAT + bn + (idx & 15) * 8) * 2) = d;
        }
    }
}

// ------------- bf16 MFMA GEMM: split-K partials or full, double-buffered -----
// K-loop: 2 x 32 KB LDS buffers; per iter {__syncthreads() [waits chunk ki's
// gloads (only outstanding VMEM) + publishes + certifies all reads of the
// other buffer done]; stage chunk ki+1 into other buffer; compute chunk ki}.
// Accumulation order unchanged -> bit-identical.
// colLimit: epilogue skips cols >= colLimit (cr only needs 64 of 128 cols).
// Optional fusion: attUpool != null -> last grid block computes the att
// softmax weight vector (fence-free: wv is only read by the NEXT dispatch).
__global__ __launch_bounds__(256) void gemm_bf16(const __bf16* __restrict__ A,
                                                 const __bf16* __restrict__ Bt,
                                                 const float* __restrict__ bias,
                                                 __bf16* __restrict__ out_bf,
                                                 float* __restrict__ out_f32,
                                                 int N, int strideK, int kIters,
                                                 int Mout, int relu, int sliceStride,
                                                 int nbx, int nby, int colLimit,
                                                 const float* __restrict__ attUpool,
                                                 const float* __restrict__ W_att,
                                                 const float* __restrict__ b_att,
                                                 float* __restrict__ wvec)
{
    __shared__ __align__(16) char smem[65536];   // dbuf d: A s-halves @d*32768+{0,8192},
                                                 //         B s-halves @d*32768+16384+{0,8192}
    const int t = threadIdx.x;

    if (attUpool != nullptr && blockIdx.x == gridDim.x - 1) {
        // ---- fused att block: pooled mean -> matvec (W_att via 16KB LDS
        // ---- quarters) -> softmax -> wvec[3200]. k-order 0..127 preserved.
        float* sW   = (float*)smem;                    // [32][128] quarter
        float* s_pm = (float*)(smem + 16384);
        float* s_at = (float*)(smem + 16384 + 512);
        float* s_dg = (float*)(smem + 16384 + 1024);
        if (t < C_CH) {
            float a = 0.f;
            for (int p = 0; p < N_CLASS; ++p) a += attUpool[(size_t)p * C_CH + t];
            s_pm[t] = a * (1.0f / (N_CLASS * 25));
        }
        __syncthreads();
        float acc = (t < C_CH) ? b_att[t] : 0.f;
#pragma unroll
        for (int qtr = 0; qtr < 4; ++qtr) {
            const float4* src = (const float4*)(W_att + qtr * 32 * C_CH);
            float4* dst = (float4*)sW;
#pragma unroll
            for (int i = 0; i < 4; ++i) dst[i * 256 + t] = src[i * 256 + t];
            __syncthreads();
            if (t < C_CH) {
#pragma unroll
                for (int k = 0; k < 32; ++k)
                    acc += s_pm[qtr * 32 + k] * sW[k * C_CH + t];
            }
            __syncthreads();
        }
        if (t < C_CH) s_at[t] = acc;
        __syncthreads();
        if (t < C_CH) {
            float m = -INFINITY;
            for (int k = 0; k < C_CH; ++k) m = fmaxf(m, s_at[k]);
            float s = 0.f;
            for (int k = 0; k < C_CH; ++k) s += expf(s_at[k] - m);
            s_dg[t] = expf(acc - m) / s * (float)C_CH;
        }
        __syncthreads();
        for (int j = t; j < D_FEAT; j += 256) wvec[j] = s_dg[j / 25];
        return;
    }

    int bx, by, ks;
    {
        const int nbxy = nbx * nby;
        ks = blockIdx.x / nbxy;
        const int b = blockIdx.x - ks * nbxy;
        const int fg = nbx >> 3;
        const int full = fg * 8 * nby;
        if (b < full) {
            const int g = b / (8 * nby);
            const int r = b - g * 8 * nby;
            bx = g * 8 + (r & 7);
            by = r >> 3;
        } else {
            const int rem = nbx - fg * 8;
            const int r = b - full;
            bx = fg * 8 + r % rem;
            by = r / rem;
        }
    }

    const int lane = t & 63;
    const int w    = t >> 6;
    const int wm   = w >> 1;
    const int wn   = w & 1;
    const int bm   = by * 128;
    const int bn   = bx * 128;

    const int q    = lane >> 4;
    const int r16  = lane & 15;
    const int sw   = (r16 >> 1) & 3;
    const int cA   = (q ^ sw) * 8;

    const int srow   = w * 16 + (lane >> 2);
    const int sglob8 = (((lane & 3) ^ ((lane >> 3) & 3))) * 8;

    const int kBase = ks * kIters * 64;
    floatx4 acc[4][4] = {};

    auto stageb = [&](int ki, char* base) {
        const int k0 = kBase + ki * 64;
#pragma unroll
        for (int s = 0; s < 2; ++s) {
#pragma unroll
            for (int j = 0; j < 2; ++j) {
                const __bf16* ga = A  + (size_t)(bm + j * 64 + srow) * strideK
                                      + k0 + s * 32 + sglob8;
                const __bf16* gb = Bt + (size_t)(bn + j * 64 + srow) * strideK
                                      + k0 + s * 32 + sglob8;
                char* la = base +         s * 8192 + (j * 256 + w * 64) * 16;
                char* lb = base + 16384 + s * 8192 + (j * 256 + w * 64) * 16;
                __builtin_amdgcn_global_load_lds((gptr_t)ga, (lptr_t)la, 16, 0, 0);
                __builtin_amdgcn_global_load_lds((gptr_t)gb, (lptr_t)lb, 16, 0, 0);
            }
        }
    };

    stageb(0, smem);
    for (int ki = 0; ki < kIters; ++ki) {
        char* base = smem + (ki & 1) * 32768;
        __syncthreads();   // waits chunk ki (vmcnt 0) + publishes; WAR-safe for
                           // the other buffer (all its ds_reads preceded this)
        if (ki + 1 < kIters) stageb(ki + 1, smem + ((ki + 1) & 1) * 32768);

#pragma unroll
        for (int s = 0; s < 2; ++s) {
            const __bf16* sAe = (const __bf16*)(base +         s * 8192);
            const __bf16* sBe = (const __bf16*)(base + 16384 + s * 8192);
            bf16x8 av[4], bv[4];
#pragma unroll
            for (int mi = 0; mi < 4; ++mi)
                av[mi] = *(const bf16x8*)(sAe + ((wm * 64 + mi * 16 + r16) * 32 + cA));
#pragma unroll
            for (int ni = 0; ni < 4; ++ni)
                bv[ni] = *(const bf16x8*)(sBe + ((wn * 64 + ni * 16 + r16) * 32 + cA));
#pragma unroll
            for (int mi = 0; mi < 4; ++mi)
#pragma unroll
                for (int ni = 0; ni < 4; ++ni)
                    acc[mi][ni] = __builtin_amdgcn_mfma_f32_16x16x32_bf16(
                        av[mi], bv[ni], acc[mi][ni], 0, 0, 0);
        }
    }

#pragma unroll
    for (int ni = 0; ni < 4; ++ni) {
        const int col = bn + wn * 64 + ni * 16 + r16;
        if (col < colLimit) {
            const float bcol = sliceStride ? 0.f : bias[col];
#pragma unroll
            for (int mi = 0; mi < 4; ++mi) {
#pragma unroll
                for (int reg = 0; reg < 4; ++reg) {
                    const int row = bm + wm * 64 + mi * 16 + q * 4 + reg;
                    if (row < Mout) {
                        if (sliceStride) {
                            out_f32[(size_t)ks * sliceStride + (size_t)row * N + col] =
                                acc[mi][ni][reg];
                        } else {
                            float v = acc[mi][ni][reg] + bcol;
                            if (relu) v = fmaxf(v, 0.f);
                            if (out_f32) out_f32[(size_t)row * N + col] = v;
                            else         out_bf [(size_t)row * N + col] = (__bf16)v;
                        }
                    }
                }
            }
        }
    }
}

// ---- fused dispatch: blocks 0..127 = support means + channel pools;
// ---- blocks 128.. = W_fine f32 -> Wfb + WfTb (bf16), 64x64 tiles:
// ---- 256B read segments, 128B write segments both layouts. LDS 16.64 KB.
__global__ __launch_bounds__(256) void ut_conv_kernel(const __bf16* __restrict__ z_share,
                                                      const float* __restrict__ W_fine,
                                                      __bf16* __restrict__ u,
                                                      float* __restrict__ upool,
                                                      __bf16* __restrict__ Wfb,
                                                      __bf16* __restrict__ WfTb)
{
    __shared__ __align__(16) char smem_u[16640];   // max(64*65*4, D_FEAT*4)
    const int b = blockIdx.x;
    const int t = threadIdx.x;

    if (b >= 128) {
        // W_fine dual-layout conversion: one 64x64 tile
        float (*tile)[65] = (float(*)[65])smem_u;
        const int tb = b - 128;
        const int tx = t & 63;
        const int ty = t >> 6;           // 0..3
        const int n0 = (tb % 50) * 64;
        const int k0 = (tb / 50) * 64;
#pragma unroll
        for (int i = ty; i < 64; i += 4) {
            const float v = W_fine[(size_t)(k0 + i) * D_FEAT + n0 + tx];
            Wfb[(size_t)(k0 + i) * D_FEAT + n0 + tx] = (__bf16)v;   // 128B rows
            tile[i][tx] = v;
        }
        __syncthreads();
#pragma unroll
        for (int i = ty; i < 64; i += 4)
            WfTb[(size_t)(n0 + i) * D_FEAT + k0 + tx] = (__bf16)tile[tx][i];  // 128B
        return;
    }

    float* srow_ = (float*)smem_u;
    const int p = b;                 // 0..127
    if (p >= N_CLASS) {
        for (int k = t; k < D_FEAT; k += 256) u[(size_t)p * D_FEAT + k] = (__bf16)0.f;
        return;
    }
    const __bf16* base = z_share + (size_t)(p * N_SUPPORT) * D_FEAT;
    for (int k = t; k < D_FEAT; k += 256) {
        float s = 0.f;
#pragma unroll
        for (int ss = 0; ss < N_SUPPORT; ++ss) s += (float)base[(size_t)ss * D_FEAT + k];
        s *= (1.0f / N_SUPPORT);
        u[(size_t)p * D_FEAT + k] = (__bf16)s;
        srow_[k] = s;
    }
    __syncthreads();
    if (t < C_CH) {
        float pool = 0.f;
#pragma unroll
        for (int win = 0; win < 25; ++win) pool += srow_[t * 25 + win];
        upool[(size_t)p * C_CH + t] = pool;
    }
}

// ---------------- y = w*(sum zp_part + bf) bf16 [128 pad][3200]; p2; c --------------
__global__ __launch_bounds__(256) void y_kernel(const float* __restrict__ zp_part,
                                                const float* __restrict__ wv,
                                                const float* __restrict__ bf,
                                                __bf16* __restrict__ y,
                                                float* __restrict__ p2,
                                                float* __restrict__ cvec)
{
    __shared__ float s_red2[8];
    const int p = blockIdx.x;        // 0..127
    const int t = threadIdx.x;
    if (p >= N_CLASS) {
        for (int j = t; j < D_FEAT; j += 256) y[(size_t)p * D_FEAT + j] = (__bf16)0.f;
        return;
    }
    float s2 = 0.f, sc = 0.f;
    for (int j = t; j < D_FEAT; j += 256) {
        float zpf = bf[j];
#pragma unroll
        for (int ss = 0; ss < NKS; ++ss)
            zpf += zp_part[(size_t)ss * ZP_SLICE + (size_t)p * D_FEAT + j];
        const float wj = wv[j];
        y[(size_t)p * D_FEAT + j] = (__bf16)(wj * zpf);
        s2 += wj * zpf * zpf;
        sc += bf[j] * wj * zpf;
    }
    s2 = waveReduceSum(s2);
    sc = waveReduceSum(sc);
    const int lane = t & 63, wid = t >> 6;
    if (lane == 0) { s_red2[wid] = s2; s_red2[4 + wid] = sc; }
    __syncthreads();
    if (t == 0) {
        p2[p]   = s_red2[0] + s_red2[1] + s_red2[2] + s_red2[3];
        cvec[p] = s_red2[4] + s_red2[5] + s_red2[6] + s_red2[7];
    }
}

// ---------------- Gt[p][k] bf16 = sum of NKS fp32 slices [128][3200] ----------------
__global__ __launch_bounds__(256) void gtsum_kernel(const float* __restrict__ gp,
                                                    __bf16* __restrict__ Gt)
{
    const int i4 = blockIdx.x * 256 + threadIdx.x;     // over 409600/4
    if (i4 >= GT_SLICE / 4) return;
    float4 s = make_float4(0.f, 0.f, 0.f, 0.f);
#pragma unroll
    for (int ss = 0; ss < NKS; ++ss) {
        const float4 v = *(const float4*)(gp + (size_t)ss * GT_SLICE + i4 * 4);
        s.x += v.x; s.y += v.y; s.z += v.z; s.w += v.w;
    }
    bf16x4 o = { (__bf16)s.x, (__bf16)s.y, (__bf16)s.z, (__bf16)s.w };
    *(bf16x4*)(Gt + (size_t)i4 * 4) = o;
}

// ---------------- softmax/loss: one wave per query, block partials (no atomics) -----
__global__ __launch_bounds__(256) void loss_kernel(const float* __restrict__ cross_part,
                                                   const float* __restrict__ p2,
                                                   const float* __restrict__ cvec,
                                                   float* __restrict__ lpart)
{
    __shared__ float s_l[4], s_a[4];
    const int t = threadIdx.x;
    const int lane = t & 63, wid = t >> 6;
    const int i = blockIdx.x * 4 + wid;       // query 0..4095
    float cr = 0.f;
#pragma unroll
    for (int ss = 0; ss < NKS; ++ss)
        cr += cross_part[(size_t)ss * CR_SLICE + (size_t)i * 128 + lane];
    const float neg = 2.0f * (cr + cvec[lane]) - p2[lane];   // -(dist) + const/row
    float m = neg;
    for (int off = 32; off > 0; off >>= 1) m = fmaxf(m, __shfl_xor(m, off, 64));
    float e = expf(neg - m);
    float ssum = e;
    for (int off = 32; off > 0; off >>= 1) ssum += __shfl_xor(ssum, off, 64);
    const float lse = m + logf(ssum);
    const int tcls = i >> 6;
    const float negt = __shfl(neg, tcls, 64);
    float v = -neg; int bi = lane;            // argmin dist == argmax neg, first on tie
    for (int off = 32; off > 0; off >>= 1) {
        const float ov = __shfl_xor(v, off, 64);
        const int   oi = __shfl_xor(bi, off, 64);
        if (ov < v || (ov == v && oi < bi)) { v = ov; bi = oi; }
    }
    if (lane == 0) { s_l[wid] = lse - negt; s_a[wid] = (bi == tcls) ? 1.0f : 0.0f; }
    __syncthreads();
    if (t == 0) {
        lpart[blockIdx.x]             = s_l[0] + s_l[1] + s_l[2] + s_l[3];
        lpart[LOSS_BLKS + blockIdx.x] = s_a[0] + s_a[1] + s_a[2] + s_a[3];
    }
}

__global__ __launch_bounds__(256) void writeout_kernel(const float* __restrict__ lpart,
                                                       float* __restrict__ out)
{
    __shared__ float s_red2[8];
    const int t = threadIdx.x;
    float l = 0.f, a = 0.f;
    for (int k = t; k < LOSS_BLKS; k += 256) {
        l += lpart[k];
        a += lpart[LOSS_BLKS + k];
    }
    l = waveReduceSum(l);
    a = waveReduceSum(a);
    const int lane = t & 63, wid = t >> 6;
    if (lane == 0) { s_red2[wid] = l; s_red2[4 + wid] = a; }
    __syncthreads();
    if (t == 0) {
        out[0] = (s_red2[0] + s_red2[1] + s_red2[2] + s_red2[3]) * (1.0f / NQ);
        out[1] = (s_red2[4] + s_red2[5] + s_red2[6] + s_red2[7]) * (1.0f / NQ);
    }
}

extern "C" void kernel_launch(void* const* d_in, const int* in_sizes, int n_in,
                              void* d_out, int out_size, void* d_ws, size_t ws_size,
                              hipStream_t stream)
{
    const float* xs      = (const float*)d_in[0];
    const float* xq      = (const float*)d_in[1];
    const float* W_share = (const float*)d_in[2];
    const float* b_share = (const float*)d_in[3];
    const float* W_att   = (const float*)d_in[4];
    const float* b_att   = (const float*)d_in[5];
    const float* W_fine  = (const float*)d_in[6];
    const float* b_fine  = (const float*)d_in[7];
    float* out = (float*)d_out;

    char* ws = (char*)d_ws;
    unsigned char* Xf8  = (unsigned char*)(ws + WS_XF8);
    unsigned char* Wsf8 = (unsigned char*)(ws + WS_WSF8);
    __bf16* Zsb     = (__bf16*)(ws + WS_ZSB);
    __bf16* Wfb     = (__bf16*)(ws + WS_WFB);
    __bf16* WfTb    = (__bf16*)(ws + WS_WFTB);
    float*  arena   = (float*) (ws + WS_ARENA);
    float*  zp_part = arena;                  // 10*204800*4 =  8,192,000
    float*  gt_part = arena;                  // 10*409600*4 = 16,384,000
    float*  cr_part = arena;                  // 10*524288*4 = 20,971,520
    __bf16* ub      = (__bf16*)(ws + WS_UB);
    __bf16* yb      = (__bf16*)(ws + WS_YB);
    __bf16* Gt      = (__bf16*)(ws + WS_GT);
    float*  wv      = (float*) (ws + WS_WV);
    float*  p2v     = (float*) (ws + WS_P2);
    float*  cvec    = (float*) (ws + WS_CVEC);
    float*  lpart   = (float*) (ws + WS_LPART);
    float*  upool   = (float*) (ws + WS_UPOOL);  // own slot (att overlaps zp)

    // prep: x->fp8 [4480][1024] | W_share^T->fp8 x64 [3200][1024] (64x64 tiles)
    prep_kernel<<<PREP_X + PREP_WS, 256, 0, stream>>>(xs, xq, W_share, Xf8, Wsf8);

    // z_share = relu((x @ W_share)*1/64 + b_share) [4416][3200] bf16
    // 128^2-tile 3-resident fp8 GEMM, single barrier per K-chunk (R8 mapping)
    gemm_fp8_128<<<GEMM8_BLKS, 256, 0, stream>>>(Xf8, Wsf8, b_share, Zsb);

    // support means + channel pools, fused with W_fine 64x64 conversion
    ut_conv_kernel<<<128 + CONV64, 256, 0, stream>>>(Zsb, W_fine, ub, upool,
                                                     Wfb, WfTb);

    // zp_part[ks][p][j] = partial u @ Wf  (A=u, Bt=WfTb)  M=64, N=3200, K=3200
    // + fused att tail block (grid 251): upool -> matvec -> softmax -> wv
    gemm_bf16<<<25 * NKS + 1, 256, 0, stream>>>(
        ub, WfTb, nullptr, nullptr, zp_part,
        D_FEAT, D_FEAT, 5, N_CLASS, 0, ZP_SLICE, 25, 1, D_FEAT,
        upool, W_att, b_att, wv);

    // y = w*(zp+b_fine), p2, c   (sums the NKS zp partials)
    y_kernel<<<128, 256, 0, stream>>>(zp_part, wv, b_fine, yb, p2v, cvec);

    // gt_part[ks][p][k] = partial y @ Wf^T  (A=yb, Bt=Wfb natural)  M=128, N=3200
    gemm_bf16<<<25 * NKS, 256, 0, stream>>>(
        yb, Wfb, nullptr, nullptr, gt_part,
        D_FEAT, D_FEAT, 5, 128, 0, GT_SLICE, 25, 1, D_FEAT,
        nullptr, nullptr, nullptr, nullptr);

    // Gt bf16 = sum of slices
    gtsum_kernel<<<(GT_SLICE / 4 + 255) / 256, 256, 0, stream>>>(gt_part, Gt);

    // cr_part[ks][i][p] = partial zs_q @ Gt^T  [4096][128]; only cols 0..63
    // are ever read by loss (classes) -> colLimit 64 halves the write
    gemm_bf16<<<32 * NKS, 256, 0, stream>>>(
        Zsb + (size_t)NS * D_FEAT, Gt, nullptr, nullptr, cr_part,
        128, D_FEAT, 5, NQ, 0, CR_SLICE, 1, 32, 64,
        nullptr, nullptr, nullptr, nullptr);

    // per-query log-softmax + loss/acc -> block partials (no atomics)
    loss_kernel<<<LOSS_BLKS, 256, 0, stream>>>(cr_part, p2v, cvec, lpart);

    // final reduction ends with PLAIN STORES to d_out (R10 lesson: no atomics
    // to the output buffer)
    writeout_kernel<<<1, 256, 0, stream>>>(lpart, out);
}

// Round 13
// 217.491 us; speedup vs baseline: 1.1134x; 1.0117x over previous
//
#include <hip/hip_runtime.h>
#include <math.h>

// Problem constants
#define N_CLASS 64
#define N_SUPPORT 5
#define N_QUERY 64
#define D_IN 1024
#define C_CH 128
#define WIN 5
#define D_FEAT 3200            // C*WIN*WIN
#define NS 320                 // N_CLASS*N_SUPPORT
#define NQ 4096                // N_CLASS*N_QUERY
#define M_ROWS 4416            // NS+NQ
#define M_PAD 4480             // 35 * 128 (fp8 gemm M tiles)

#define ZP_SLICE  (N_CLASS * D_FEAT)          // 204800
#define GT_SLICE  (128 * D_FEAT)              // 409600
#define CR_SLICE  (NQ * 128)                  // 524288
#define NKS       10                          // split-K slices
#define LOSS_BLKS (NQ / 4)                    // 1024

// prep kernel block-range partition
#define PREP_X   4480                          // x->fp8 blocks (4480 rows)
#define PREP_WS  800                           // W_share 64x64 tiles (16 x 50)
#define CONV64   2500                          // W_fine 64x64 conversion tiles
#define GEMM8_BLKS (35 * 25)                   // fp8 gemm blocks (row-major, R8 best)

#define WS_SCALE    64.0f                      // W_share fp8 pre-scale (avoids denormals)
#define WS_INVSCALE 0.015625f

// workspace offsets (bytes)
#define WS_XF8      0u          // [4480][1024] fp8        4,587,520
#define WS_WSF8     4718592u    // [3200][1024] fp8        3,276,800
#define WS_ZSB      8126464u    // [4416][3200] bf16      28,262,400
#define WS_WFB      36388864u   // natural  [k][j] bf16   20,480,000
#define WS_WFTB     56868864u   // transposed [j][k] bf16 20,480,000
#define WS_ARENA    77348864u   // fp32 arena             20,971,520
#define WS_UB       98320384u   // [128][3200] bf16          819,200
#define WS_YB       99139584u   // [128][3200] bf16          819,200
#define WS_GT       99958784u   // [128][3200] bf16          819,200
#define WS_WV       100777984u  //                            12,800
#define WS_P2       100790784u
#define WS_CVEC     100791296u
#define WS_LPART    100791808u  // 8,192
#define WS_UPOOL    100800128u  // [64][128] f32 (own slot: the fused att block
                                // reads it WHILE zp partials overwrite the arena)

// NOTE (round-2): no producer->consumer fusion across blocks in one dispatch --
// the per-block __threadfence() is an L2 writeback on MI355X (-> 60us).
// NOTE (rounds 4-6): bulk-BW work must not share a dispatch with the MFMA
// pipeline; write-segment size dominates conversion throughput.
// NOTE (round-7): LDS is declared in BYTES; check LDS_Block_Size each round.
// NOTE (round-9): XCD-band remap of the fp8 GEMM grid was within noise ->
// simple row-major (R8, measured best).
// NOTE (round-10): atomicAdd to d_out cost +22us (output buffer is
// fine-grained/host-visible). Final reductions end with PLAIN STORES to d_out.
// NOTE (round-12): split-K bf16 GEMMs were depth-1-pipelined (vmcnt-0 drain
// per K-step, MfmaUtil 1.5%, ~1 block/CU -> no TLP). Ported the fp8 GEMM's
// counted-vmcnt 3-slot schedule (BK=32, 48KB LDS): 2 chunks always in flight.

typedef __bf16 bf16x8 __attribute__((ext_vector_type(8)));
typedef __bf16 bf16x4 __attribute__((ext_vector_type(4)));
typedef float floatx4 __attribute__((ext_vector_type(4)));
typedef __attribute__((address_space(1))) const void* gptr_t;
typedef __attribute__((address_space(3))) void* lptr_t;

__device__ __forceinline__ float waveReduceSum(float v) {
    for (int off = 32; off > 0; off >>= 1) v += __shfl_xor(v, off, 64);
    return v;
}

// ------ prep: x->fp8 | W_share^T->fp8(x64), 64x64 tiles. Rows with bit1 set
// ------ get their 8B halves swapped inside each 16B unit (half-level bit of
// ------ the 64B-row octet swizzle p = o ^ ((row>>1)&7); the unit-level XOR
// ------ (row>>2)&3 is applied on the gload source address in the fp8 GEMM).
__global__ __launch_bounds__(256) void prep_kernel(const float* __restrict__ xs,
                                                   const float* __restrict__ xq,
                                                   const float* __restrict__ W_share,
                                                   unsigned char* __restrict__ Xf8,
                                                   unsigned char* __restrict__ Wsf8)
{
    __shared__ float tile[64][65];   // 16,640 B
    const int b = blockIdx.x;
    const int t = threadIdx.x;

    if (b < PREP_X) {
        // x (xs|xq|zero-pad) -> fp8 e4m3 [4480][1024], 4 elems per thread
        const int e = (b * 256 + t) * 4;
        const int row = e >> 10;
        const int col = e & 1023;
        float4 v = make_float4(0.f, 0.f, 0.f, 0.f);
        if (row < NS)          v = *(const float4*)(xs + (size_t)row * D_IN + col);
        else if (row < M_ROWS) v = *(const float4*)(xq + (size_t)(row - NS) * D_IN + col);
        int p = __builtin_amdgcn_cvt_pk_fp8_f32(v.x, v.y, 0, false);
        p     = __builtin_amdgcn_cvt_pk_fp8_f32(v.z, v.w, p, true);
        const int ocol = col ^ (((row >> 1) & 1) << 3);     // half-swap on row bit1
        *(int*)(Xf8 + (size_t)row * D_IN + ocol) = p;
        return;
    }
    // W_share [1024][3200] -> Wsf8 [3200][1024] fp8, scaled x64, half-swapped.
    // 64x64 tile: load rows k0+i (256B segs), store rows n0+i (64B segs).
    const int tx = t & 63;
    const int ty = t >> 6;           // 0..3
    const int tb = b - PREP_X;
    const int n0 = (tb % 50) * 64;
    const int k0 = (tb / 50) * 64;
#pragma unroll
    for (int i = ty; i < 64; i += 4)
        tile[i][tx] = W_share[(size_t)(k0 + i) * D_FEAT + n0 + tx];
    __syncthreads();
#pragma unroll
    for (int i = ty; i < 64; i += 4) {
        const int p = __builtin_amdgcn_cvt_pk_fp8_f32(tile[tx][i] * WS_SCALE, 0.f,
                                                      0, false);
        const int n = n0 + i;
        const int k = (k0 + tx) ^ (((n >> 1) & 1) << 3);    // half-swap on row bit1
        Wsf8[(size_t)n * D_IN + k] = (unsigned char)(p & 0xff);
    }
}

// -------- fp8 MFMA GEMM, 128^2 tile, ONE barrier per 64B K-chunk ------------
// out = relu(A @ Bt^T * 1/64 + bias), A [4480][1024] fp8, Bt [3200][1024] fp8.
// 256 threads = 4 waves (2M x 2N), per-wave output 64x64, acc[4][4].
// LDS: 3 rotating slots x 16 KB = 48 KB -> 3 blocks/CU resident (875 blocks).
// Per chunk u: {vmcnt(4); barrier [publishes u + certifies u-1's reads done];
// 16x ds_read_b64; stage(u+2); lgkmcnt(0); setprio(1); 32 MFMA; setprio(0)}.
// Accumulation order per acc element unchanged -> bit-identical results.
// LDS swizzle: stored octet p = o ^ ((row>>1)&7) -> conflict-free b64 reads;
// realized as source-unit XOR ((row>>2)&3) on gload addr + prep's half-swap.
__global__ __launch_bounds__(256, 3) void gemm_fp8_128(const unsigned char* __restrict__ A,
                                                       const unsigned char* __restrict__ Bt,
                                                       const float* __restrict__ bias,
                                                       __bf16* __restrict__ out_bf)
{
    __shared__ __align__(16) unsigned char smem[49152];

    const int t    = threadIdx.x;
    const int lane = t & 63;
    const int w    = t >> 6;        // 0..3
    const int wm   = w >> 1;
    const int wn   = w & 1;

    const int bx = blockIdx.x % 25;
    const int by = blockIdx.x / 25;
    const int bm = by * 128;
    const int bn = bx * 128;

    const int q    = lane >> 4;     // k-octet group 0..3
    const int r16  = lane & 15;
    const int m3   = (r16 >> 1) & 7;
    const int off0 = (q ^ m3) * 8;  // half-0 swizzled byte offset; half-1: ^32

    const int rowA = (wm * 64 + r16) * 64;    // + mi*1024
    const int rowB = (wn * 64 + r16) * 64;    // + ni*1024

    // staging: thread t covers (row = t>>2 within a 64-row half, 16B unit t&3)
    const int srow  = t >> 2;
    const int sunit = 16 * ((t & 3) ^ ((srow >> 2) & 3));   // source-unit XOR

    const unsigned char* gA = A  + (size_t)(bm + srow) * D_IN + sunit;
    const unsigned char* gB = Bt + (size_t)(bn + srow) * D_IN + sunit;

    auto stage = [&](int uu, int slot) {
        const unsigned char* ga = gA + uu * 64;
        const unsigned char* gb = gB + uu * 64;
        unsigned char* l = smem + slot * 16384 + t * 16;
        __builtin_amdgcn_global_load_lds((gptr_t)ga,           (lptr_t)l,            16, 0, 0);
        __builtin_amdgcn_global_load_lds((gptr_t)(ga + 65536), (lptr_t)(l + 4096),   16, 0, 0);
        __builtin_amdgcn_global_load_lds((gptr_t)gb,           (lptr_t)(l + 8192),   16, 0, 0);
        __builtin_amdgcn_global_load_lds((gptr_t)(gb + 65536), (lptr_t)(l + 12288),  16, 0, 0);
    };

    floatx4 acc[4][4] = {};
    long av0[4], bv0[4], av1[4], bv1[4];

    auto ld16 = [&](const unsigned char* sa) {
#pragma unroll
        for (int mi = 0; mi < 4; ++mi)
            av0[mi] = *(const long*)(sa + rowA + mi * 1024 + off0);
#pragma unroll
        for (int ni = 0; ni < 4; ++ni)
            bv0[ni] = *(const long*)(sa + 8192 + rowB + ni * 1024 + off0);
#pragma unroll
        for (int mi = 0; mi < 4; ++mi)
            av1[mi] = *(const long*)(sa + rowA + mi * 1024 + (off0 ^ 32));
#pragma unroll
        for (int ni = 0; ni < 4; ++ni)
            bv1[ni] = *(const long*)(sa + 8192 + rowB + ni * 1024 + (off0 ^ 32));
    };
    auto mfma32 = [&]() {
        __builtin_amdgcn_s_setprio(1);
#pragma unroll
        for (int mi = 0; mi < 4; ++mi)
#pragma unroll
            for (int ni = 0; ni < 4; ++ni)
                acc[mi][ni] = __builtin_amdgcn_mfma_f32_16x16x32_fp8_fp8(
                    av0[mi], bv0[ni], acc[mi][ni], 0, 0, 0);
#pragma unroll
        for (int mi = 0; mi < 4; ++mi)
#pragma unroll
            for (int ni = 0; ni < 4; ++ni)
                acc[mi][ni] = __builtin_amdgcn_mfma_f32_16x16x32_fp8_fp8(
                    av1[mi], bv1[ni], acc[mi][ni], 0, 0, 0);
        __builtin_amdgcn_s_setprio(0);
    };

    // prologue: chunks 0,1 in flight (8 loads/thread)
    stage(0, 0);
    stage(1, 1);

    for (int u = 0; u < 14; ++u) {
        const unsigned char* sa = smem + (u % 3) * 16384;
        asm volatile("s_waitcnt vmcnt(4)" ::: "memory");   // chunk u landed
        __builtin_amdgcn_s_barrier();
        ld16(sa);
        stage(u + 2, (u + 2) % 3);
        asm volatile("s_waitcnt lgkmcnt(0)" ::: "memory");
        mfma32();
    }
    {   // u = 14: chunk 15 still in flight, nothing left to stage
        const unsigned char* sa = smem + (14 % 3) * 16384;
        asm volatile("s_waitcnt vmcnt(4)" ::: "memory");
        __builtin_amdgcn_s_barrier();
        ld16(sa);
        asm volatile("s_waitcnt lgkmcnt(0)" ::: "memory");
        mfma32();
    }
    {   // u = 15: drain
        const unsigned char* sa = smem + (15 % 3) * 16384;
        asm volatile("s_waitcnt vmcnt(0)" ::: "memory");
        __builtin_amdgcn_s_barrier();
        ld16(sa);
        asm volatile("s_waitcnt lgkmcnt(0)" ::: "memory");
        mfma32();
    }

    // ---- epilogue: acc -> bf16 via LDS (XOR-swizzled, conflict-free) ->
    // ---- coalesced 256B-row global stores. LDS tile [128][256B] @ smem[0].
    __syncthreads();                 // all frag reads done before overwrite
    float bcol[4];
#pragma unroll
    for (int ni = 0; ni < 4; ++ni) bcol[ni] = bias[bn + wn * 64 + ni * 16 + r16];
    // addr = row*256 + ((col*2) ^ (q<<5)); row = wm*64+mi*16+q*4+reg,
    // col = wn*64+ni*16+r16  ->  base + mi*4096 + reg*256 + ((ni^q)<<5)
    const int ebase = (wm * 64 + q * 4) * 256 + wn * 128 + r16 * 2;
#pragma unroll
    for (int mi = 0; mi < 4; ++mi)
#pragma unroll
        for (int ni = 0; ni < 4; ++ni) {
            const int cb2 = (ni ^ q) << 5;
#pragma unroll
            for (int reg = 0; reg < 4; ++reg) {
                float v = acc[mi][ni][reg] * WS_INVSCALE + bcol[ni];
                v = fmaxf(v, 0.f);
                *(__bf16*)(smem + ebase + mi * 4096 + reg * 256 + cb2) = (__bf16)v;
            }
        }
    __syncthreads();
#pragma unroll
    for (int ps = 0; ps < 8; ++ps) {
        const int idx  = ps * 256 + t;
        const int row  = idx >> 4;           // 0..127
        const int grow = bm + row;
        if (grow < M_ROWS) {
            const int lb = row * 256 + (((idx & 15) << 4) ^ (((row >> 2) & 3) << 5));
            const int4 d = *(const int4*)(smem + lb);
            *(int4*)((char*)out_bf + ((size_t)grow * D_FEAT + bn + (idx & 15) * 8) * 2) = d;
        }
    }
}

// ------------- bf16 MFMA GEMM: split-K partials or full ----------------------
// Counted-vmcnt 3-slot pipeline (ported from the fp8 GEMM, R12): BK=32 chunks,
// LDS 3 x 16 KB (A 8KB | B 8KB per slot) = 48 KB -> up to 3 blocks/CU.
// Per chunk u: {vmcnt(4) [chunk u's 4 gloads landed, u+1 in flight]; barrier
// [publishes u + certifies u-1's ds_reads done: each wave's lgkmcnt(0)
// precedes its MFMA, which precedes its arrival here]; 8x ds_read_b128;
// stage(u+2) into slot (u+2)%3; lgkmcnt(0); 16 MFMA}. Never vmcnt(0) in loop.
// Accumulation per acc element: ascending 32-k MFMA steps, identical order to
// the old 64-chunk/2-half version -> bit-identical.
// colLimit: epilogue skips cols >= colLimit (cr only needs 64 of 128 cols).
// Optional fusion: attUpool != null -> last grid block computes the att
// softmax weight vector (fence-free: wv is only read by the NEXT dispatch).
__global__ __launch_bounds__(256) void gemm_bf16(const __bf16* __restrict__ A,
                                                 const __bf16* __restrict__ Bt,
                                                 const float* __restrict__ bias,
                                                 __bf16* __restrict__ out_bf,
                                                 float* __restrict__ out_f32,
                                                 int N, int strideK, int kIters,
                                                 int Mout, int relu, int sliceStride,
                                                 int nbx, int nby, int colLimit,
                                                 const float* __restrict__ attUpool,
                                                 const float* __restrict__ W_att,
                                                 const float* __restrict__ b_att,
                                                 float* __restrict__ wvec)
{
    __shared__ __align__(16) char smem[49152];   // slot s: A @s*16384, B @s*16384+8192
    const int t = threadIdx.x;

    if (attUpool != nullptr && blockIdx.x == gridDim.x - 1) {
        // ---- fused att block: pooled mean -> matvec (W_att via 16KB LDS
        // ---- quarters) -> softmax -> wvec[3200]. k-order 0..127 preserved.
        float* sW   = (float*)smem;                    // [32][128] quarter
        float* s_pm = (float*)(smem + 16384);
        float* s_at = (float*)(smem + 16384 + 512);
        float* s_dg = (float*)(smem + 16384 + 1024);
        if (t < C_CH) {
            float a = 0.f;
            for (int p = 0; p < N_CLASS; ++p) a += attUpool[(size_t)p * C_CH + t];
            s_pm[t] = a * (1.0f / (N_CLASS * 25));
        }
        __syncthreads();
        float acc = (t < C_CH) ? b_att[t] : 0.f;
#pragma unroll
        for (int qtr = 0; qtr < 4; ++qtr) {
            const float4* src = (const float4*)(W_att + qtr * 32 * C_CH);
            float4* dst = (float4*)sW;
#pragma unroll
            for (int i = 0; i < 4; ++i) dst[i * 256 + t] = src[i * 256 + t];
            __syncthreads();
            if (t < C_CH) {
#pragma unroll
                for (int k = 0; k < 32; ++k)
                    acc += s_pm[qtr * 32 + k] * sW[k * C_CH + t];
            }
            __syncthreads();
        }
        if (t < C_CH) s_at[t] = acc;
        __syncthreads();
        if (t < C_CH) {
            float m = -INFINITY;
            for (int k = 0; k < C_CH; ++k) m = fmaxf(m, s_at[k]);
            float s = 0.f;
            for (int k = 0; k < C_CH; ++k) s += expf(s_at[k] - m);
            s_dg[t] = expf(acc - m) / s * (float)C_CH;
        }
        __syncthreads();
        for (int j = t; j < D_FEAT; j += 256) wvec[j] = s_dg[j / 25];
        return;
    }

    int bx, by, ks;
    {
        const int nbxy = nbx * nby;
        ks = blockIdx.x / nbxy;
        const int b = blockIdx.x - ks * nbxy;
        const int fg = nbx >> 3;
        const int full = fg * 8 * nby;
        if (b < full) {
            const int g = b / (8 * nby);
            const int r = b - g * 8 * nby;
            bx = g * 8 + (r & 7);
            by = r >> 3;
        } else {
            const int rem = nbx - fg * 8;
            const int r = b - full;
            bx = fg * 8 + r % rem;
            by = r / rem;
        }
    }

    const int lane = t & 63;
    const int w    = t >> 6;
    const int wm   = w >> 1;
    const int wn   = w & 1;
    const int bm   = by * 128;
    const int bn   = bx * 128;

    const int q    = lane >> 4;
    const int r16  = lane & 15;
    const int sw   = (r16 >> 1) & 3;
    const int cA   = (q ^ sw) * 8;

    const int srow   = w * 16 + (lane >> 2);
    const int sglob8 = (((lane & 3) ^ ((lane >> 3) & 3))) * 8;

    const int kBase = ks * kIters * 32;
    floatx4 acc[4][4] = {};

    // stage chunk ki (32 k) into slot: 4 gloads/thread (A j=0,1 | B j=0,1)
    auto stageb = [&](int ki, int slot) {
        const int k0 = kBase + ki * 32;
        char* base = smem + slot * 16384;
#pragma unroll
        for (int j = 0; j < 2; ++j) {
            const __bf16* ga = A  + (size_t)(bm + j * 64 + srow) * strideK
                                  + k0 + sglob8;
            const __bf16* gb = Bt + (size_t)(bn + j * 64 + srow) * strideK
                                  + k0 + sglob8;
            char* la = base +        j * 4096 + w * 1024;
            char* lb = base + 8192 + j * 4096 + w * 1024;
            __builtin_amdgcn_global_load_lds((gptr_t)ga, (lptr_t)la, 16, 0, 0);
            __builtin_amdgcn_global_load_lds((gptr_t)gb, (lptr_t)lb, 16, 0, 0);
        }
    };

    bf16x8 av[4], bv[4];
    auto ldfrags = [&](const char* base) {
        const __bf16* sAe = (const __bf16*)base;
        const __bf16* sBe = (const __bf16*)(base + 8192);
#pragma unroll
        for (int mi = 0; mi < 4; ++mi)
            av[mi] = *(const bf16x8*)(sAe + ((wm * 64 + mi * 16 + r16) * 32 + cA));
#pragma unroll
        for (int ni = 0; ni < 4; ++ni)
            bv[ni] = *(const bf16x8*)(sBe + ((wn * 64 + ni * 16 + r16) * 32 + cA));
    };
    auto mfma16 = [&]() {
#pragma unroll
        for (int mi = 0; mi < 4; ++mi)
#pragma unroll
            for (int ni = 0; ni < 4; ++ni)
                acc[mi][ni] = __builtin_amdgcn_mfma_f32_16x16x32_bf16(
                    av[mi], bv[ni], acc[mi][ni], 0, 0, 0);
    };

    // prologue: chunks 0,1 in flight (8 gloads/thread)
    stageb(0, 0);
    stageb(1, 1);

    for (int u = 0; u < kIters; ++u) {
        const char* base = smem + (u % 3) * 16384;
        if (u + 1 < kIters)
            asm volatile("s_waitcnt vmcnt(4)" ::: "memory");  // chunk u landed
        else
            asm volatile("s_waitcnt vmcnt(0)" ::: "memory");  // last chunk
        __builtin_amdgcn_s_barrier();
        ldfrags(base);
        if (u + 2 < kIters) stageb(u + 2, (u + 2) % 3);
        asm volatile("s_waitcnt lgkmcnt(0)" ::: "memory");
        mfma16();
    }

#pragma unroll
    for (int ni = 0; ni < 4; ++ni) {
        const int col = bn + wn * 64 + ni * 16 + r16;
        if (col < colLimit) {
            const float bcol = sliceStride ? 0.f : bias[col];
#pragma unroll
            for (int mi = 0; mi < 4; ++mi) {
#pragma unroll
                for (int reg = 0; reg < 4; ++reg) {
                    const int row = bm + wm * 64 + mi * 16 + q * 4 + reg;
                    if (row < Mout) {
                        if (sliceStride) {
                            out_f32[(size_t)ks * sliceStride + (size_t)row * N + col] =
                                acc[mi][ni][reg];
                        } else {
                            float v = acc[mi][ni][reg] + bcol;
                            if (relu) v = fmaxf(v, 0.f);
                            if (out_f32) out_f32[(size_t)row * N + col] = v;
                            else         out_bf [(size_t)row * N + col] = (__bf16)v;
                        }
                    }
                }
            }
        }
    }
}

// ---- fused dispatch: blocks 0..127 = support means + channel pools;
// ---- blocks 128.. = W_fine f32 -> Wfb + WfTb (bf16), 64x64 tiles:
// ---- 256B read segments, 128B write segments both layouts. LDS 16.64 KB.
__global__ __launch_bounds__(256) void ut_conv_kernel(const __bf16* __restrict__ z_share,
                                                      const float* __restrict__ W_fine,
                                                      __bf16* __restrict__ u,
                                                      float* __restrict__ upool,
                                                      __bf16* __restrict__ Wfb,
                                                      __bf16* __restrict__ WfTb)
{
    __shared__ __align__(16) char smem_u[16640];   // max(64*65*4, D_FEAT*4)
    const int b = blockIdx.x;
    const int t = threadIdx.x;

    if (b >= 128) {
        // W_fine dual-layout conversion: one 64x64 tile
        float (*tile)[65] = (float(*)[65])smem_u;
        const int tb = b - 128;
        const int tx = t & 63;
        const int ty = t >> 6;           // 0..3
        const int n0 = (tb % 50) * 64;
        const int k0 = (tb / 50) * 64;
#pragma unroll
        for (int i = ty; i < 64; i += 4) {
            const float v = W_fine[(size_t)(k0 + i) * D_FEAT + n0 + tx];
            Wfb[(size_t)(k0 + i) * D_FEAT + n0 + tx] = (__bf16)v;   // 128B rows
            tile[i][tx] = v;
        }
        __syncthreads();
#pragma unroll
        for (int i = ty; i < 64; i += 4)
            WfTb[(size_t)(n0 + i) * D_FEAT + k0 + tx] = (__bf16)tile[tx][i];  // 128B
        return;
    }

    float* srow_ = (float*)smem_u;
    const int p = b;                 // 0..127
    if (p >= N_CLASS) {
        for (int k = t; k < D_FEAT; k += 256) u[(size_t)p * D_FEAT + k] = (__bf16)0.f;
        return;
    }
    const __bf16* base = z_share + (size_t)(p * N_SUPPORT) * D_FEAT;
    for (int k = t; k < D_FEAT; k += 256) {
        float s = 0.f;
#pragma unroll
        for (int ss = 0; ss < N_SUPPORT; ++ss) s += (float)base[(size_t)ss * D_FEAT + k];
        s *= (1.0f / N_SUPPORT);
        u[(size_t)p * D_FEAT + k] = (__bf16)s;
        srow_[k] = s;
    }
    __syncthreads();
    if (t < C_CH) {
        float pool = 0.f;
#pragma unroll
        for (int win = 0; win < 25; ++win) pool += srow_[t * 25 + win];
        upool[(size_t)p * C_CH + t] = pool;
    }
}

// ---------------- y = w*(sum zp_part + bf) bf16 [128 pad][3200]; p2; c --------------
__global__ __launch_bounds__(256) void y_kernel(const float* __restrict__ zp_part,
                                                const float* __restrict__ wv,
                                                const float* __restrict__ bf,
                                                __bf16* __restrict__ y,
                                                float* __restrict__ p2,
                                                float* __restrict__ cvec)
{
    __shared__ float s_red2[8];
    const int p = blockIdx.x;        // 0..127
    const int t = threadIdx.x;
    if (p >= N_CLASS) {
        for (int j = t; j < D_FEAT; j += 256) y[(size_t)p * D_FEAT + j] = (__bf16)0.f;
        return;
    }
    float s2 = 0.f, sc = 0.f;
    for (int j = t; j < D_FEAT; j += 256) {
        float zpf = bf[j];
#pragma unroll
        for (int ss = 0; ss < NKS; ++ss)
            zpf += zp_part[(size_t)ss * ZP_SLICE + (size_t)p * D_FEAT + j];
        const float wj = wv[j];
        y[(size_t)p * D_FEAT + j] = (__bf16)(wj * zpf);
        s2 += wj * zpf * zpf;
        sc += bf[j] * wj * zpf;
    }
    s2 = waveReduceSum(s2);
    sc = waveReduceSum(sc);
    const int lane = t & 63, wid = t >> 6;
    if (lane == 0) { s_red2[wid] = s2; s_red2[4 + wid] = sc; }
    __syncthreads();
    if (t == 0) {
        p2[p]   = s_red2[0] + s_red2[1] + s_red2[2] + s_red2[3];
        cvec[p] = s_red2[4] + s_red2[5] + s_red2[6] + s_red2[7];
    }
}

// ---------------- Gt[p][k] bf16 = sum of NKS fp32 slices [128][3200] ----------------
__global__ __launch_bounds__(256) void gtsum_kernel(const float* __restrict__ gp,
                                                    __bf16* __restrict__ Gt)
{
    const int i4 = blockIdx.x * 256 + threadIdx.x;     // over 409600/4
    if (i4 >= GT_SLICE / 4) return;
    float4 s = make_float4(0.f, 0.f, 0.f, 0.f);
#pragma unroll
    for (int ss = 0; ss < NKS; ++ss) {
        const float4 v = *(const float4*)(gp + (size_t)ss * GT_SLICE + i4 * 4);
        s.x += v.x; s.y += v.y; s.z += v.z; s.w += v.w;
    }
    bf16x4 o = { (__bf16)s.x, (__bf16)s.y, (__bf16)s.z, (__bf16)s.w };
    *(bf16x4*)(Gt + (size_t)i4 * 4) = o;
}

// ---------------- softmax/loss: one wave per query, block partials (no atomics) -----
__global__ __launch_bounds__(256) void loss_kernel(const float* __restrict__ cross_part,
                                                   const float* __restrict__ p2,
                                                   const float* __restrict__ cvec,
                                                   float* __restrict__ lpart)
{
    __shared__ float s_l[4], s_a[4];
    const int t = threadIdx.x;
    const int lane = t & 63, wid = t >> 6;
    const int i = blockIdx.x * 4 + wid;       // query 0..4095
    float cr = 0.f;
#pragma unroll
    for (int ss = 0; ss < NKS; ++ss)
        cr += cross_part[(size_t)ss * CR_SLICE + (size_t)i * 128 + lane];
    const float neg = 2.0f * (cr + cvec[lane]) - p2[lane];   // -(dist) + const/row
    float m = neg;
    for (int off = 32; off > 0; off >>= 1) m = fmaxf(m, __shfl_xor(m, off, 64));
    float e = expf(neg - m);
    float ssum = e;
    for (int off = 32; off > 0; off >>= 1) ssum += __shfl_xor(ssum, off, 64);
    const float lse = m + logf(ssum);
    const int tcls = i >> 6;
    const float negt = __shfl(neg, tcls, 64);
    float v = -neg; int bi = lane;            // argmin dist == argmax neg, first on tie
    for (int off = 32; off > 0; off >>= 1) {
        const float ov = __shfl_xor(v, off, 64);
        const int   oi = __shfl_xor(bi, off, 64);
        if (ov < v || (ov == v && oi < bi)) { v = ov; bi = oi; }
    }
    if (lane == 0) { s_l[wid] = lse - negt; s_a[wid] = (bi == tcls) ? 1.0f : 0.0f; }
    __syncthreads();
    if (t == 0) {
        lpart[blockIdx.x]             = s_l[0] + s_l[1] + s_l[2] + s_l[3];
        lpart[LOSS_BLKS + blockIdx.x] = s_a[0] + s_a[1] + s_a[2] + s_a[3];
    }
}

__global__ __launch_bounds__(256) void writeout_kernel(const float* __restrict__ lpart,
                                                       float* __restrict__ out)
{
    __shared__ float s_red2[8];
    const int t = threadIdx.x;
    float l = 0.f, a = 0.f;
    for (int k = t; k < LOSS_BLKS; k += 256) {
        l += lpart[k];
        a += lpart[LOSS_BLKS + k];
    }
    l = waveReduceSum(l);
    a = waveReduceSum(a);
    const int lane = t & 63, wid = t >> 6;
    if (lane == 0) { s_red2[wid] = l; s_red2[4 + wid] = a; }
    __syncthreads();
    if (t == 0) {
        out[0] = (s_red2[0] + s_red2[1] + s_red2[2] + s_red2[3]) * (1.0f / NQ);
        out[1] = (s_red2[4] + s_red2[5] + s_red2[6] + s_red2[7]) * (1.0f / NQ);
    }
}

extern "C" void kernel_launch(void* const* d_in, const int* in_sizes, int n_in,
                              void* d_out, int out_size, void* d_ws, size_t ws_size,
                              hipStream_t stream)
{
    const float* xs      = (const float*)d_in[0];
    const float* xq      = (const float*)d_in[1];
    const float* W_share = (const float*)d_in[2];
    const float* b_share = (const float*)d_in[3];
    const float* W_att   = (const float*)d_in[4];
    const float* b_att   = (const float*)d_in[5];
    const float* W_fine  = (const float*)d_in[6];
    const float* b_fine  = (const float*)d_in[7];
    float* out = (float*)d_out;

    char* ws = (char*)d_ws;
    unsigned char* Xf8  = (unsigned char*)(ws + WS_XF8);
    unsigned char* Wsf8 = (unsigned char*)(ws + WS_WSF8);
    __bf16* Zsb     = (__bf16*)(ws + WS_ZSB);
    __bf16* Wfb     = (__bf16*)(ws + WS_WFB);
    __bf16* WfTb    = (__bf16*)(ws + WS_WFTB);
    float*  arena   = (float*) (ws + WS_ARENA);
    float*  zp_part = arena;                  // 10*204800*4 =  8,192,000
    float*  gt_part = arena;                  // 10*409600*4 = 16,384,000
    float*  cr_part = arena;                  // 10*524288*4 = 20,971,520
    __bf16* ub      = (__bf16*)(ws + WS_UB);
    __bf16* yb      = (__bf16*)(ws + WS_YB);
    __bf16* Gt      = (__bf16*)(ws + WS_GT);
    float*  wv      = (float*) (ws + WS_WV);
    float*  p2v     = (float*) (ws + WS_P2);
    float*  cvec    = (float*) (ws + WS_CVEC);
    float*  lpart   = (float*) (ws + WS_LPART);
    float*  upool   = (float*) (ws + WS_UPOOL);  // own slot (att overlaps zp)

    // prep: x->fp8 [4480][1024] | W_share^T->fp8 x64 [3200][1024] (64x64 tiles)
    prep_kernel<<<PREP_X + PREP_WS, 256, 0, stream>>>(xs, xq, W_share, Xf8, Wsf8);

    // z_share = relu((x @ W_share)*1/64 + b_share) [4416][3200] bf16
    // 128^2-tile 3-resident fp8 GEMM, single barrier per K-chunk (R8 mapping)
    gemm_fp8_128<<<GEMM8_BLKS, 256, 0, stream>>>(Xf8, Wsf8, b_share, Zsb);

    // support means + channel pools, fused with W_fine 64x64 conversion
    ut_conv_kernel<<<128 + CONV64, 256, 0, stream>>>(Zsb, W_fine, ub, upool,
                                                     Wfb, WfTb);

    // zp_part[ks][p][j] = partial u @ Wf  (A=u, Bt=WfTb)  M=64, N=3200, K=3200
    // kIters=10 (BK=32) + fused att tail block (grid 251)
    gemm_bf16<<<25 * NKS + 1, 256, 0, stream>>>(
        ub, WfTb, nullptr, nullptr, zp_part,
        D_FEAT, D_FEAT, 10, N_CLASS, 0, ZP_SLICE, 25, 1, D_FEAT,
        upool, W_att, b_att, wv);

    // y = w*(zp+b_fine), p2, c   (sums the NKS zp partials)
    y_kernel<<<128, 256, 0, stream>>>(zp_part, wv, b_fine, yb, p2v, cvec);

    // gt_part[ks][p][k] = partial y @ Wf^T  (A=yb, Bt=Wfb natural)  M=128, N=3200
    gemm_bf16<<<25 * NKS, 256, 0, stream>>>(
        yb, Wfb, nullptr, nullptr, gt_part,
        D_FEAT, D_FEAT, 10, 128, 0, GT_SLICE, 25, 1, D_FEAT,
        nullptr, nullptr, nullptr, nullptr);

    // Gt bf16 = sum of slices
    gtsum_kernel<<<(GT_SLICE / 4 + 255) / 256, 256, 0, stream>>>(gt_part, Gt);

    // cr_part[ks][i][p] = partial zs_q @ Gt^T  [4096][128]; only cols 0..63
    // are ever read by loss (classes) -> colLimit 64 halves the write
    gemm_bf16<<<32 * NKS, 256, 0, stream>>>(
        Zsb + (size_t)NS * D_FEAT, Gt, nullptr, nullptr, cr_part,
        128, D_FEAT, 10, NQ, 0, CR_SLICE, 1, 32, 64,
        nullptr, nullptr, nullptr, nullptr);

    // per-query log-softmax + loss/acc -> block partials (no atomics)
    loss_kernel<<<LOSS_BLKS, 256, 0, stream>>>(cr_part, p2v, cvec, lpart);

    // final reduction ends with PLAIN STORES to d_out (R10 lesson)
    writeout_kernel<<<1, 256, 0, stream>>>(lpart, out);
}

// Round 14
// 211.496 us; speedup vs baseline: 1.1450x; 1.0283x over previous
//
#include <hip/hip_runtime.h>
#include <math.h>

// Problem constants
#define N_CLASS 64
#define N_SUPPORT 5
#define N_QUERY 64
#define D_IN 1024
#define C_CH 128
#define WIN 5
#define D_FEAT 3200            // C*WIN*WIN
#define NS 320                 // N_CLASS*N_SUPPORT
#define NQ 4096                // N_CLASS*N_QUERY
#define M_ROWS 4416            // NS+NQ
#define M_PAD 4480             // 35 * 128 (fp8 gemm M tiles)

#define ZP_SLICE  (N_CLASS * D_FEAT)          // 204800
#define GT_SLICE  (N_CLASS * D_FEAT)          // 204800 (R13: gt only needs 64 rows)
#define CR_SLICE  (NQ * 128)                  // 524288
#define NKS       10                          // split-K slices
#define LOSS_BLKS (NQ / 4)                    // 1024

// prep kernel block-range partition
#define PREP_X   4480                          // x->fp8 blocks (4480 rows)
#define PREP_WS  800                           // W_share 64x64 tiles (16 x 50)
#define CONV64   2500                          // W_fine 64x64 conversion tiles
#define GEMM8_BLKS (35 * 25)                   // fp8 gemm blocks (row-major, R8 best)

#define WS_SCALE    64.0f                      // W_share fp8 pre-scale (avoids denormals)
#define WS_INVSCALE 0.015625f

// workspace offsets (bytes)
#define WS_XF8      0u          // [4480][1024] fp8        4,587,520
#define WS_WSF8     4718592u    // [3200][1024] fp8        3,276,800
#define WS_ZSB      8126464u    // [4416][3200] bf16      28,262,400
#define WS_WFB      36388864u   // natural  [k][j] bf16   20,480,000
#define WS_WFTB     56868864u   // transposed [j][k] bf16 20,480,000
#define WS_ARENA    77348864u   // fp32 arena             20,971,520
#define WS_UB       98320384u   // [128][3200] bf16          819,200
#define WS_YB       99139584u   // [128][3200] bf16          819,200
#define WS_GT       99958784u   // [128][3200] bf16          819,200
#define WS_WV       100777984u  //                            12,800
#define WS_P2       100790784u
#define WS_CVEC     100791296u
#define WS_LPART    100791808u  // 8,192
#define WS_UPOOL    100800128u  // [64][128] f32 (own slot: the fused att block
                                // reads it WHILE zp partials overwrite the arena)

// NOTE (round-2): no producer->consumer fusion across blocks in one dispatch --
// the per-block __threadfence() is an L2 writeback on MI355X (-> 60us).
// NOTE (rounds 4-6): bulk-BW work must not share a dispatch with the MFMA
// pipeline; write-segment size dominates conversion throughput.
// NOTE (round-7): LDS is declared in BYTES; check LDS_Block_Size each round.
// NOTE (round-9): XCD-band remap of the fp8 GEMM grid was within noise.
// NOTE (round-10): atomicAdd to d_out cost +22us. Final reductions end with
// PLAIN STORES to d_out; workspace atomics are fine.
// NOTE (round-12): counted-vmcnt 3-slot pipeline in the bf16 GEMMs (~neutral).
// NOTE (round-13): half of every split-K GEMM tile was computing discarded
// values (zp M=64 of 128; gt rows 64-127 feed only discarded cr cols; cr cols
// 64-127 discarded). Rectangular tiles <4,2>=64Mx128N (zp,gt), <2,4>=128Mx64N
// (cr): 8 MFMA + 3 gloads per chunk (was 16+4); gt_part/gtsum traffic halved.

typedef __bf16 bf16x8 __attribute__((ext_vector_type(8)));
typedef __bf16 bf16x4 __attribute__((ext_vector_type(4)));
typedef float floatx4 __attribute__((ext_vector_type(4)));
typedef __attribute__((address_space(1))) const void* gptr_t;
typedef __attribute__((address_space(3))) void* lptr_t;

__device__ __forceinline__ float waveReduceSum(float v) {
    for (int off = 32; off > 0; off >>= 1) v += __shfl_xor(v, off, 64);
    return v;
}

// ------ prep: x->fp8 | W_share^T->fp8(x64), 64x64 tiles. Rows with bit1 set
// ------ get their 8B halves swapped inside each 16B unit (half-level bit of
// ------ the 64B-row octet swizzle p = o ^ ((row>>1)&7); the unit-level XOR
// ------ (row>>2)&3 is applied on the gload source address in the fp8 GEMM).
__global__ __launch_bounds__(256) void prep_kernel(const float* __restrict__ xs,
                                                   const float* __restrict__ xq,
                                                   const float* __restrict__ W_share,
                                                   unsigned char* __restrict__ Xf8,
                                                   unsigned char* __restrict__ Wsf8)
{
    __shared__ float tile[64][65];   // 16,640 B
    const int b = blockIdx.x;
    const int t = threadIdx.x;

    if (b < PREP_X) {
        // x (xs|xq|zero-pad) -> fp8 e4m3 [4480][1024], 4 elems per thread
        const int e = (b * 256 + t) * 4;
        const int row = e >> 10;
        const int col = e & 1023;
        float4 v = make_float4(0.f, 0.f, 0.f, 0.f);
        if (row < NS)          v = *(const float4*)(xs + (size_t)row * D_IN + col);
        else if (row < M_ROWS) v = *(const float4*)(xq + (size_t)(row - NS) * D_IN + col);
        int p = __builtin_amdgcn_cvt_pk_fp8_f32(v.x, v.y, 0, false);
        p     = __builtin_amdgcn_cvt_pk_fp8_f32(v.z, v.w, p, true);
        const int ocol = col ^ (((row >> 1) & 1) << 3);     // half-swap on row bit1
        *(int*)(Xf8 + (size_t)row * D_IN + ocol) = p;
        return;
    }
    // W_share [1024][3200] -> Wsf8 [3200][1024] fp8, scaled x64, half-swapped.
    const int tx = t & 63;
    const int ty = t >> 6;           // 0..3
    const int tb = b - PREP_X;
    const int n0 = (tb % 50) * 64;
    const int k0 = (tb / 50) * 64;
#pragma unroll
    for (int i = ty; i < 64; i += 4)
        tile[i][tx] = W_share[(size_t)(k0 + i) * D_FEAT + n0 + tx];
    __syncthreads();
#pragma unroll
    for (int i = ty; i < 64; i += 4) {
        const int p = __builtin_amdgcn_cvt_pk_fp8_f32(tile[tx][i] * WS_SCALE, 0.f,
                                                      0, false);
        const int n = n0 + i;
        const int k = (k0 + tx) ^ (((n >> 1) & 1) << 3);    // half-swap on row bit1
        Wsf8[(size_t)n * D_IN + k] = (unsigned char)(p & 0xff);
    }
}

// -------- fp8 MFMA GEMM, 128^2 tile, ONE barrier per 64B K-chunk ------------
// (unchanged from R12 -- measured best)
__global__ __launch_bounds__(256, 3) void gemm_fp8_128(const unsigned char* __restrict__ A,
                                                       const unsigned char* __restrict__ Bt,
                                                       const float* __restrict__ bias,
                                                       __bf16* __restrict__ out_bf)
{
    __shared__ __align__(16) unsigned char smem[49152];

    const int t    = threadIdx.x;
    const int lane = t & 63;
    const int w    = t >> 6;        // 0..3
    const int wm   = w >> 1;
    const int wn   = w & 1;

    const int bx = blockIdx.x % 25;
    const int by = blockIdx.x / 25;
    const int bm = by * 128;
    const int bn = bx * 128;

    const int q    = lane >> 4;     // k-octet group 0..3
    const int r16  = lane & 15;
    const int m3   = (r16 >> 1) & 7;
    const int off0 = (q ^ m3) * 8;  // half-0 swizzled byte offset; half-1: ^32

    const int rowA = (wm * 64 + r16) * 64;    // + mi*1024
    const int rowB = (wn * 64 + r16) * 64;    // + ni*1024

    const int srow  = t >> 2;
    const int sunit = 16 * ((t & 3) ^ ((srow >> 2) & 3));   // source-unit XOR

    const unsigned char* gA = A  + (size_t)(bm + srow) * D_IN + sunit;
    const unsigned char* gB = Bt + (size_t)(bn + srow) * D_IN + sunit;

    auto stage = [&](int uu, int slot) {
        const unsigned char* ga = gA + uu * 64;
        const unsigned char* gb = gB + uu * 64;
        unsigned char* l = smem + slot * 16384 + t * 16;
        __builtin_amdgcn_global_load_lds((gptr_t)ga,           (lptr_t)l,            16, 0, 0);
        __builtin_amdgcn_global_load_lds((gptr_t)(ga + 65536), (lptr_t)(l + 4096),   16, 0, 0);
        __builtin_amdgcn_global_load_lds((gptr_t)gb,           (lptr_t)(l + 8192),   16, 0, 0);
        __builtin_amdgcn_global_load_lds((gptr_t)(gb + 65536), (lptr_t)(l + 12288),  16, 0, 0);
    };

    floatx4 acc[4][4] = {};
    long av0[4], bv0[4], av1[4], bv1[4];

    auto ld16 = [&](const unsigned char* sa) {
#pragma unroll
        for (int mi = 0; mi < 4; ++mi)
            av0[mi] = *(const long*)(sa + rowA + mi * 1024 + off0);
#pragma unroll
        for (int ni = 0; ni < 4; ++ni)
            bv0[ni] = *(const long*)(sa + 8192 + rowB + ni * 1024 + off0);
#pragma unroll
        for (int mi = 0; mi < 4; ++mi)
            av1[mi] = *(const long*)(sa + rowA + mi * 1024 + (off0 ^ 32));
#pragma unroll
        for (int ni = 0; ni < 4; ++ni)
            bv1[ni] = *(const long*)(sa + 8192 + rowB + ni * 1024 + (off0 ^ 32));
    };
    auto mfma32 = [&]() {
        __builtin_amdgcn_s_setprio(1);
#pragma unroll
        for (int mi = 0; mi < 4; ++mi)
#pragma unroll
            for (int ni = 0; ni < 4; ++ni)
                acc[mi][ni] = __builtin_amdgcn_mfma_f32_16x16x32_fp8_fp8(
                    av0[mi], bv0[ni], acc[mi][ni], 0, 0, 0);
#pragma unroll
        for (int mi = 0; mi < 4; ++mi)
#pragma unroll
            for (int ni = 0; ni < 4; ++ni)
                acc[mi][ni] = __builtin_amdgcn_mfma_f32_16x16x32_fp8_fp8(
                    av1[mi], bv1[ni], acc[mi][ni], 0, 0, 0);
        __builtin_amdgcn_s_setprio(0);
    };

    stage(0, 0);
    stage(1, 1);

    for (int u = 0; u < 14; ++u) {
        const unsigned char* sa = smem + (u % 3) * 16384;
        asm volatile("s_waitcnt vmcnt(4)" ::: "memory");   // chunk u landed
        __builtin_amdgcn_s_barrier();
        ld16(sa);
        stage(u + 2, (u + 2) % 3);
        asm volatile("s_waitcnt lgkmcnt(0)" ::: "memory");
        mfma32();
    }
    {   // u = 14
        const unsigned char* sa = smem + (14 % 3) * 16384;
        asm volatile("s_waitcnt vmcnt(4)" ::: "memory");
        __builtin_amdgcn_s_barrier();
        ld16(sa);
        asm volatile("s_waitcnt lgkmcnt(0)" ::: "memory");
        mfma32();
    }
    {   // u = 15: drain
        const unsigned char* sa = smem + (15 % 3) * 16384;
        asm volatile("s_waitcnt vmcnt(0)" ::: "memory");
        __builtin_amdgcn_s_barrier();
        ld16(sa);
        asm volatile("s_waitcnt lgkmcnt(0)" ::: "memory");
        mfma32();
    }

    __syncthreads();                 // all frag reads done before overwrite
    float bcol[4];
#pragma unroll
    for (int ni = 0; ni < 4; ++ni) bcol[ni] = bias[bn + wn * 64 + ni * 16 + r16];
    const int ebase = (wm * 64 + q * 4) * 256 + wn * 128 + r16 * 2;
#pragma unroll
    for (int mi = 0; mi < 4; ++mi)
#pragma unroll
        for (int ni = 0; ni < 4; ++ni) {
            const int cb2 = (ni ^ q) << 5;
#pragma unroll
            for (int reg = 0; reg < 4; ++reg) {
                float v = acc[mi][ni][reg] * WS_INVSCALE + bcol[ni];
                v = fmaxf(v, 0.f);
                *(__bf16*)(smem + ebase + mi * 4096 + reg * 256 + cb2) = (__bf16)v;
            }
        }
    __syncthreads();
#pragma unroll
    for (int ps = 0; ps < 8; ++ps) {
        const int idx  = ps * 256 + t;
        const int row  = idx >> 4;           // 0..127
        const int grow = bm + row;
        if (grow < M_ROWS) {
            const int lb = row * 256 + (((idx & 15) << 4) ^ (((row >> 2) & 3) << 5));
            const int4 d = *(const int4*)(smem + lb);
            *(int4*)((char*)out_bf + ((size_t)grow * D_FEAT + bn + (idx & 15) * 8) * 2) = d;
        }
    }
}

// ------------- bf16 MFMA GEMM, rectangular tiles (R13) ----------------------
// <MI=4,NI=2>: 64M x 128N tile (zp, gt -- only 64 output rows exist/needed).
// <MI=2,NI=4>: 128M x 64N tile (cr -- only 64 output cols needed).
// Counted-vmcnt 3-slot pipeline (R12): BK=32 chunks, slot = (RA+RB)*64 =
// 12,288 B, 3 slots = 36,864 B LDS. 3 gloads/chunk (192 rows), vmcnt(3).
// Per chunk u: {vmcnt(3); barrier [publishes u + certifies u-1's reads done];
// MI+NI ds_read_b128; stage(u+2); lgkmcnt(0); MI*NI MFMA}.
// Accumulation per retained acc element: identical ascending-k order ->
// bit-identical outputs. Swizzle (sglob8 write / cA read, keyed on row bits
// 1-2 which come from r16 at 16-row granularity) carries over unchanged.
// Optional fusion: attUpool != null -> last grid block computes the att
// softmax weight vector (fence-free; wv read only by the NEXT dispatch).
template<int MI, int NI>
__global__ __launch_bounds__(256) void gemm_bf16_t(const __bf16* __restrict__ A,
                                                   const __bf16* __restrict__ Bt,
                                                   float* __restrict__ out_f32,
                                                   int N, int strideK, int kIters,
                                                   int Mout, int sliceStride,
                                                   int nbx, int nby,
                                                   const float* __restrict__ attUpool,
                                                   const float* __restrict__ W_att,
                                                   const float* __restrict__ b_att,
                                                   float* __restrict__ wvec)
{
    constexpr int RA   = (MI == 4) ? 64 : 128;   // A-tile rows staged
    constexpr int RB   = (NI == 4) ? 64 : 128;   // B-tile rows staged
    constexpr int SLOT = (RA + RB) * 64;         // 12,288 B

    __shared__ __align__(16) char smem[3 * SLOT];   // 36,864 B
    const int t = threadIdx.x;

    if (attUpool != nullptr && blockIdx.x == gridDim.x - 1) {
        // ---- fused att block: pooled mean -> matvec (W_att via 16KB LDS
        // ---- quarters) -> softmax -> wvec[3200]. k-order 0..127 preserved.
        float* sW   = (float*)smem;                    // [32][128] quarter
        float* s_pm = (float*)(smem + 16384);
        float* s_at = (float*)(smem + 16384 + 512);
        float* s_dg = (float*)(smem + 16384 + 1024);
        if (t < C_CH) {
            float a = 0.f;
            for (int p = 0; p < N_CLASS; ++p) a += attUpool[(size_t)p * C_CH + t];
            s_pm[t] = a * (1.0f / (N_CLASS * 25));
        }
        __syncthreads();
        float acc = (t < C_CH) ? b_att[t] : 0.f;
#pragma unroll
        for (int qtr = 0; qtr < 4; ++qtr) {
            const float4* src = (const float4*)(W_att + qtr * 32 * C_CH);
            float4* dst = (float4*)sW;
#pragma unroll
            for (int i = 0; i < 4; ++i) dst[i * 256 + t] = src[i * 256 + t];
            __syncthreads();
            if (t < C_CH) {
#pragma unroll
                for (int k = 0; k < 32; ++k)
                    acc += s_pm[qtr * 32 + k] * sW[k * C_CH + t];
            }
            __syncthreads();
        }
        if (t < C_CH) s_at[t] = acc;
        __syncthreads();
        if (t < C_CH) {
            float m = -INFINITY;
            for (int k = 0; k < C_CH; ++k) m = fmaxf(m, s_at[k]);
            float s = 0.f;
            for (int k = 0; k < C_CH; ++k) s += expf(s_at[k] - m);
            s_dg[t] = expf(acc - m) / s * (float)C_CH;
        }
        __syncthreads();
        for (int j = t; j < D_FEAT; j += 256) wvec[j] = s_dg[j / 25];
        return;
    }

    int bx, by, ks;
    {
        const int nbxy = nbx * nby;
        ks = blockIdx.x / nbxy;
        const int b = blockIdx.x - ks * nbxy;
        bx = b % nbx;
        by = b / nbx;
    }

    const int lane = t & 63;
    const int w    = t >> 6;
    const int bm   = by * RA;       // 64-row tiles for MI=4; 128-row for MI=2
    const int bn   = bx * RB;

    const int q    = lane >> 4;
    const int r16  = lane & 15;
    const int sw   = (r16 >> 1) & 3;
    const int cA   = (q ^ sw) * 8;

    const int sglob8 = (((t & 3) ^ ((t >> 3) & 3))) * 8;

    const int kBase = ks * kIters * 32;
    floatx4 acc[MI][NI] = {};

    // stage chunk ki: 3 gloads/thread over 192 concat rows (A then B)
    auto stageb = [&](int ki, int slot) {
        const int k0 = kBase + ki * 32;
        char* base = smem + slot * SLOT;
#pragma unroll
        for (int g = 0; g < 3; ++g) {
            const int rr = g * 64 + (t >> 2);
            const __bf16* gp;
            if (g * 64 < RA)
                gp = A + (size_t)(bm + rr) * strideK + k0 + sglob8;
            else
                gp = Bt + (size_t)(bn + (rr - RA)) * strideK + k0 + sglob8;
            char* l = base + g * 4096 + t * 16;
            __builtin_amdgcn_global_load_lds((gptr_t)gp, (lptr_t)l, 16, 0, 0);
        }
    };

    bf16x8 av[MI], bv[NI];
    auto ldfrags = [&](const char* base) {
        const __bf16* sA = (const __bf16*)base;
        const __bf16* sB = (const __bf16*)(base + RA * 64);
        const int arb = (MI == 2) ? w * 32 : 0;
        const int brb = (NI == 2) ? w * 32 : 0;
#pragma unroll
        for (int mi = 0; mi < MI; ++mi)
            av[mi] = *(const bf16x8*)(sA + ((arb + mi * 16 + r16) * 32 + cA));
#pragma unroll
        for (int ni = 0; ni < NI; ++ni)
            bv[ni] = *(const bf16x8*)(sB + ((brb + ni * 16 + r16) * 32 + cA));
    };
    auto mfmaT = [&]() {
#pragma unroll
        for (int mi = 0; mi < MI; ++mi)
#pragma unroll
            for (int ni = 0; ni < NI; ++ni)
                acc[mi][ni] = __builtin_amdgcn_mfma_f32_16x16x32_bf16(
                    av[mi], bv[ni], acc[mi][ni], 0, 0, 0);
    };

    // prologue: chunks 0,1 in flight (6 gloads/thread)
    stageb(0, 0);
    stageb(1, 1);

    for (int u = 0; u < kIters; ++u) {
        const char* base = smem + (u % 3) * SLOT;
        if (u + 1 < kIters)
            asm volatile("s_waitcnt vmcnt(3)" ::: "memory");  // chunk u landed
        else
            asm volatile("s_waitcnt vmcnt(0)" ::: "memory");  // last chunk
        __builtin_amdgcn_s_barrier();
        ldfrags(base);
        if (u + 2 < kIters) stageb(u + 2, (u + 2) % 3);
        asm volatile("s_waitcnt lgkmcnt(0)" ::: "memory");
        mfmaT();
    }

    const int rb0 = bm + ((MI == 2) ? w * 32 : 0);
    const int cb0 = bn + ((NI == 2) ? w * 32 : 0);
#pragma unroll
    for (int ni = 0; ni < NI; ++ni) {
        const int col = cb0 + ni * 16 + r16;
#pragma unroll
        for (int mi = 0; mi < MI; ++mi) {
#pragma unroll
            for (int reg = 0; reg < 4; ++reg) {
                const int row = rb0 + mi * 16 + q * 4 + reg;
                if (row < Mout)
                    out_f32[(size_t)ks * sliceStride + (size_t)row * N + col] =
                        acc[mi][ni][reg];
            }
        }
    }
}

// ---- fused dispatch: blocks 0..63 = support means + channel pools;
// ---- blocks 64.. = W_fine f32 -> Wfb + WfTb (bf16), 64x64 tiles.
// ---- (ub rows 64-127 no longer written: zp's 64M tile never reads them.)
__global__ __launch_bounds__(256) void ut_conv_kernel(const __bf16* __restrict__ z_share,
                                                      const float* __restrict__ W_fine,
                                                      __bf16* __restrict__ u,
                                                      float* __restrict__ upool,
                                                      __bf16* __restrict__ Wfb,
                                                      __bf16* __restrict__ WfTb)
{
    __shared__ __align__(16) char smem_u[16640];   // max(64*65*4, D_FEAT*4)
    const int b = blockIdx.x;
    const int t = threadIdx.x;

    if (b >= 64) {
        // W_fine dual-layout conversion: one 64x64 tile
        float (*tile)[65] = (float(*)[65])smem_u;
        const int tb = b - 64;
        const int tx = t & 63;
        const int ty = t >> 6;           // 0..3
        const int n0 = (tb % 50) * 64;
        const int k0 = (tb / 50) * 64;
#pragma unroll
        for (int i = ty; i < 64; i += 4) {
            const float v = W_fine[(size_t)(k0 + i) * D_FEAT + n0 + tx];
            Wfb[(size_t)(k0 + i) * D_FEAT + n0 + tx] = (__bf16)v;   // 128B rows
            tile[i][tx] = v;
        }
        __syncthreads();
#pragma unroll
        for (int i = ty; i < 64; i += 4)
            WfTb[(size_t)(n0 + i) * D_FEAT + k0 + tx] = (__bf16)tile[tx][i];  // 128B
        return;
    }

    float* srow_ = (float*)smem_u;
    const int p = b;                 // 0..63
    const __bf16* base = z_share + (size_t)(p * N_SUPPORT) * D_FEAT;
    for (int k = t; k < D_FEAT; k += 256) {
        float s = 0.f;
#pragma unroll
        for (int ss = 0; ss < N_SUPPORT; ++ss) s += (float)base[(size_t)ss * D_FEAT + k];
        s *= (1.0f / N_SUPPORT);
        u[(size_t)p * D_FEAT + k] = (__bf16)s;
        srow_[k] = s;
    }
    __syncthreads();
    if (t < C_CH) {
        float pool = 0.f;
#pragma unroll
        for (int win = 0; win < 25; ++win) pool += srow_[t * 25 + win];
        upool[(size_t)p * C_CH + t] = pool;
    }
}

// ---------------- y = w*(sum zp_part + bf) bf16 [64][3200]; p2; c -------------------
__global__ __launch_bounds__(256) void y_kernel(const float* __restrict__ zp_part,
                                                const float* __restrict__ wv,
                                                const float* __restrict__ bf,
                                                __bf16* __restrict__ y,
                                                float* __restrict__ p2,
                                                float* __restrict__ cvec)
{
    __shared__ float s_red2[8];
    const int p = blockIdx.x;        // 0..63
    const int t = threadIdx.x;
    float s2 = 0.f, sc = 0.f;
    for (int j = t; j < D_FEAT; j += 256) {
        float zpf = bf[j];
#pragma unroll
        for (int ss = 0; ss < NKS; ++ss)
            zpf += zp_part[(size_t)ss * ZP_SLICE + (size_t)p * D_FEAT + j];
        const float wj = wv[j];
        y[(size_t)p * D_FEAT + j] = (__bf16)(wj * zpf);
        s2 += wj * zpf * zpf;
        sc += bf[j] * wj * zpf;
    }
    s2 = waveReduceSum(s2);
    sc = waveReduceSum(sc);
    const int lane = t & 63, wid = t >> 6;
    if (lane == 0) { s_red2[wid] = s2; s_red2[4 + wid] = sc; }
    __syncthreads();
    if (t == 0) {
        p2[p]   = s_red2[0] + s_red2[1] + s_red2[2] + s_red2[3];
        cvec[p] = s_red2[4] + s_red2[5] + s_red2[6] + s_red2[7];
    }
}

// ---------------- Gt[p][k] bf16 = sum of NKS fp32 slices [64][3200] -----------------
__global__ __launch_bounds__(256) void gtsum_kernel(const float* __restrict__ gp,
                                                    __bf16* __restrict__ Gt)
{
    const int i4 = blockIdx.x * 256 + threadIdx.x;     // over 204800/4
    if (i4 >= GT_SLICE / 4) return;
    float4 s = make_float4(0.f, 0.f, 0.f, 0.f);
#pragma unroll
    for (int ss = 0; ss < NKS; ++ss) {
        const float4 v = *(const float4*)(gp + (size_t)ss * GT_SLICE + i4 * 4);
        s.x += v.x; s.y += v.y; s.z += v.z; s.w += v.w;
    }
    bf16x4 o = { (__bf16)s.x, (__bf16)s.y, (__bf16)s.z, (__bf16)s.w };
    *(bf16x4*)(Gt + (size_t)i4 * 4) = o;
}

// ---------------- softmax/loss: one wave per query, block partials (no atomics) -----
__global__ __launch_bounds__(256) void loss_kernel(const float* __restrict__ cross_part,
                                                   const float* __restrict__ p2,
                                                   const float* __restrict__ cvec,
                                                   float* __restrict__ lpart)
{
    __shared__ float s_l[4], s_a[4];
    const int t = threadIdx.x;
    const int lane = t & 63, wid = t >> 6;
    const int i = blockIdx.x * 4 + wid;       // query 0..4095
    float cr = 0.f;
#pragma unroll
    for (int ss = 0; ss < NKS; ++ss)
        cr += cross_part[(size_t)ss * CR_SLICE + (size_t)i * 128 + lane];
    const float neg = 2.0f * (cr + cvec[lane]) - p2[lane];   // -(dist) + const/row
    float m = neg;
    for (int off = 32; off > 0; off >>= 1) m = fmaxf(m, __shfl_xor(m, off, 64));
    float e = expf(neg - m);
    float ssum = e;
    for (int off = 32; off > 0; off >>= 1) ssum += __shfl_xor(ssum, off, 64);
    const float lse = m + logf(ssum);
    const int tcls = i >> 6;
    const float negt = __shfl(neg, tcls, 64);
    float v = -neg; int bi = lane;            // argmin dist == argmax neg, first on tie
    for (int off = 32; off > 0; off >>= 1) {
        const float ov = __shfl_xor(v, off, 64);
        const int   oi = __shfl_xor(bi, off, 64);
        if (ov < v || (ov == v && oi < bi)) { v = ov; bi = oi; }
    }
    if (lane == 0) { s_l[wid] = lse - negt; s_a[wid] = (bi == tcls) ? 1.0f : 0.0f; }
    __syncthreads();
    if (t == 0) {
        lpart[blockIdx.x]             = s_l[0] + s_l[1] + s_l[2] + s_l[3];
        lpart[LOSS_BLKS + blockIdx.x] = s_a[0] + s_a[1] + s_a[2] + s_a[3];
    }
}

__global__ __launch_bounds__(256) void writeout_kernel(const float* __restrict__ lpart,
                                                       float* __restrict__ out)
{
    __shared__ float s_red2[8];
    const int t = threadIdx.x;
    float l = 0.f, a = 0.f;
    for (int k = t; k < LOSS_BLKS; k += 256) {
        l += lpart[k];
        a += lpart[LOSS_BLKS + k];
    }
    l = waveReduceSum(l);
    a = waveReduceSum(a);
    const int lane = t & 63, wid = t >> 6;
    if (lane == 0) { s_red2[wid] = l; s_red2[4 + wid] = a; }
    __syncthreads();
    if (t == 0) {
        out[0] = (s_red2[0] + s_red2[1] + s_red2[2] + s_red2[3]) * (1.0f / NQ);
        out[1] = (s_red2[4] + s_red2[5] + s_red2[6] + s_red2[7]) * (1.0f / NQ);
    }
}

extern "C" void kernel_launch(void* const* d_in, const int* in_sizes, int n_in,
                              void* d_out, int out_size, void* d_ws, size_t ws_size,
                              hipStream_t stream)
{
    const float* xs      = (const float*)d_in[0];
    const float* xq      = (const float*)d_in[1];
    const float* W_share = (const float*)d_in[2];
    const float* b_share = (const float*)d_in[3];
    const float* W_att   = (const float*)d_in[4];
    const float* b_att   = (const float*)d_in[5];
    const float* W_fine  = (const float*)d_in[6];
    const float* b_fine  = (const float*)d_in[7];
    float* out = (float*)d_out;

    char* ws = (char*)d_ws;
    unsigned char* Xf8  = (unsigned char*)(ws + WS_XF8);
    unsigned char* Wsf8 = (unsigned char*)(ws + WS_WSF8);
    __bf16* Zsb     = (__bf16*)(ws + WS_ZSB);
    __bf16* Wfb     = (__bf16*)(ws + WS_WFB);
    __bf16* WfTb    = (__bf16*)(ws + WS_WFTB);
    float*  arena   = (float*) (ws + WS_ARENA);
    float*  zp_part = arena;                  // 10*204800*4 =  8,192,000
    float*  gt_part = arena;                  // 10*204800*4 =  8,192,000
    float*  cr_part = arena;                  // 10*524288*4 = 20,971,520
    __bf16* ub      = (__bf16*)(ws + WS_UB);
    __bf16* yb      = (__bf16*)(ws + WS_YB);
    __bf16* Gt      = (__bf16*)(ws + WS_GT);
    float*  wv      = (float*) (ws + WS_WV);
    float*  p2v     = (float*) (ws + WS_P2);
    float*  cvec    = (float*) (ws + WS_CVEC);
    float*  lpart   = (float*) (ws + WS_LPART);
    float*  upool   = (float*) (ws + WS_UPOOL);  // own slot (att overlaps zp)

    // prep: x->fp8 [4480][1024] | W_share^T->fp8 x64 [3200][1024] (64x64 tiles)
    prep_kernel<<<PREP_X + PREP_WS, 256, 0, stream>>>(xs, xq, W_share, Xf8, Wsf8);

    // z_share = relu((x @ W_share)*1/64 + b_share) [4416][3200] bf16
    gemm_fp8_128<<<GEMM8_BLKS, 256, 0, stream>>>(Xf8, Wsf8, b_share, Zsb);

    // support means + channel pools, fused with W_fine 64x64 conversion
    ut_conv_kernel<<<64 + CONV64, 256, 0, stream>>>(Zsb, W_fine, ub, upool,
                                                    Wfb, WfTb);

    // zp_part[ks][p][j] = partial u @ Wf  (64M x 128N tiles)  M=64, N=3200
    // + fused att tail block (grid 251): upool -> matvec -> softmax -> wv
    gemm_bf16_t<4, 2><<<25 * NKS + 1, 256, 0, stream>>>(
        ub, WfTb, zp_part,
        D_FEAT, D_FEAT, 10, N_CLASS, ZP_SLICE, 25, 1,
        upool, W_att, b_att, wv);

    // y = w*(zp+b_fine), p2, c   (rows 0..63 only; gt never reads 64-127)
    y_kernel<<<64, 256, 0, stream>>>(zp_part, wv, b_fine, yb, p2v, cvec);

    // gt_part[ks][p][k] = partial y @ Wf^T  (64M x 128N)  M=64 (rows 64-127
    // of Gt fed only discarded cr cols -> never computed)
    gemm_bf16_t<4, 2><<<25 * NKS, 256, 0, stream>>>(
        yb, Wfb, gt_part,
        D_FEAT, D_FEAT, 10, N_CLASS, GT_SLICE, 25, 1,
        nullptr, nullptr, nullptr, nullptr);

    // Gt bf16 [64][3200] = sum of slices
    gtsum_kernel<<<(GT_SLICE / 4 + 255) / 256, 256, 0, stream>>>(gt_part, Gt);

    // cr_part[ks][i][p] = partial zs_q @ Gt^T  (128M x 64N)  only the 64 real
    // prototype cols are computed (row stride stays 128 for loss)
    gemm_bf16_t<2, 4><<<32 * NKS, 256, 0, stream>>>(
        Zsb + (size_t)NS * D_FEAT, Gt, cr_part,
        128, D_FEAT, 10, NQ, CR_SLICE, 1, 32,
        nullptr, nullptr, nullptr, nullptr);

    // per-query log-softmax + loss/acc -> block partials (no atomics)
    loss_kernel<<<LOSS_BLKS, 256, 0, stream>>>(cr_part, p2v, cvec, lpart);

    // final reduction ends with PLAIN STORES to d_out (R10 lesson)
    writeout_kernel<<<1, 256, 0, stream>>>(lpart, out);
}

// Round 15
// 209.221 us; speedup vs baseline: 1.1574x; 1.0109x over previous
//
#include <hip/hip_runtime.h>
#include <math.h>

// Problem constants
#define N_CLASS 64
#define N_SUPPORT 5
#define N_QUERY 64
#define D_IN 1024
#define C_CH 128
#define WIN 5
#define D_FEAT 3200            // C*WIN*WIN
#define NS 320                 // N_CLASS*N_SUPPORT
#define NQ 4096                // N_CLASS*N_QUERY
#define M_ROWS 4416            // NS+NQ
#define M_PAD 4480             // 35 * 128 (fp8 gemm M tiles)

#define ZP_SLICE  (N_CLASS * D_FEAT)          // 204800
#define GT_SLICE  (N_CLASS * D_FEAT)          // 204800 (R13: gt only needs 64 rows)
#define CR_SLICE  (NQ * 128)                  // 524288
#define NKS       10                          // split-K slices
#define LOSS_BLKS (NQ / 4)                    // 1024

// prep kernel block-range partition (R14: W_fine conversion lives here --
// pure-BW work beside pure-BW work; the R6 failure was the 32x32 segment
// inefficiency, fixed since R8 with 64x64 tiles / 128B segments)
#define PREP_X   4480                          // x->fp8 blocks (4480 rows)
#define PREP_WS  800                           // W_share 64x64 tiles (16 x 50)
#define CONV64   2500                          // W_fine 64x64 conversion tiles
#define GEMM8_BLKS (35 * 25)                   // fp8 gemm blocks (row-major, R8 best)

#define WS_SCALE    64.0f                      // W_share fp8 pre-scale (avoids denormals)
#define WS_INVSCALE 0.015625f

// workspace offsets (bytes)
#define WS_XF8      0u          // [4480][1024] fp8        4,587,520
#define WS_WSF8     4718592u    // [3200][1024] fp8        3,276,800
#define WS_ZSB      8126464u    // [4416][3200] bf16      28,262,400
#define WS_WFB      36388864u   // natural  [k][j] bf16   20,480,000
#define WS_WFTB     56868864u   // transposed [j][k] bf16 20,480,000
#define WS_ARENA    77348864u   // fp32 arena             20,971,520
#define WS_UB       98320384u   // [64][3200] bf16           409,600
#define WS_YB       99139584u   // [64][3200] bf16           409,600
#define WS_GT       99958784u   // [64][3200] bf16           409,600
#define WS_WV       100777984u  //                            12,800
#define WS_P2       100790784u
#define WS_CVEC     100791296u
#define WS_LPART    100791808u  // 8,192
#define WS_UPOOL    100800128u  // [64][128] f32 (own slot: the fused att block
                                // reads it WHILE zp partials overwrite the arena)

// NOTE (round-2): no producer->consumer fusion across blocks in one dispatch --
// the per-block __threadfence() is an L2 writeback on MI355X (-> 60us).
// NOTE (rounds 4-6): bulk-BW work must not share a dispatch with the MFMA
// pipeline; write-segment size dominates conversion throughput.
// NOTE (round-7): LDS is declared in BYTES; check LDS_Block_Size each round.
// NOTE (round-9): XCD-band remap of the fp8 GEMM grid was within noise.
// NOTE (round-10): atomicAdd to d_out cost +22us. Final reductions end with
// PLAIN STORES to d_out; workspace atomics are fine.
// NOTE (round-12): counted-vmcnt 3-slot pipeline in the bf16 GEMMs (~neutral).
// NOTE (round-13): rectangular GEMM tiles <4,2>/<2,4> eliminate the half of
// each split-K tile whose outputs were discarded (-6us, bit-identical).
// NOTE (round-14): W_fine conversion moved from its serial ut_conv slot into
// prep (BW beside BW): the ~20-25us conversion window collapses into prep's.

typedef __bf16 bf16x8 __attribute__((ext_vector_type(8)));
typedef __bf16 bf16x4 __attribute__((ext_vector_type(4)));
typedef float floatx4 __attribute__((ext_vector_type(4)));
typedef __attribute__((address_space(1))) const void* gptr_t;
typedef __attribute__((address_space(3))) void* lptr_t;

__device__ __forceinline__ float waveReduceSum(float v) {
    for (int off = 32; off > 0; off >>= 1) v += __shfl_xor(v, off, 64);
    return v;
}

// ------ prep: x->fp8 | W_share^T->fp8(x64) | W_fine f32 -> Wfb + WfTb bf16.
// ------ All pure-BW, independent blocks; 64x64 tiles (256B reads, 128B/64B
// ------ write segments). fp8 rows with bit1 set get their 8B halves swapped
// ------ inside each 16B unit (half-level bit of the 64B-row octet swizzle
// ------ p = o ^ ((row>>1)&7); unit-level XOR (row>>2)&3 applied on the gload
// ------ source address in the fp8 GEMM). Wfb/WfTb consumed 2+ dispatches on.
__global__ __launch_bounds__(256) void prep_kernel(const float* __restrict__ xs,
                                                   const float* __restrict__ xq,
                                                   const float* __restrict__ W_share,
                                                   const float* __restrict__ W_fine,
                                                   unsigned char* __restrict__ Xf8,
                                                   unsigned char* __restrict__ Wsf8,
                                                   __bf16* __restrict__ Wfb,
                                                   __bf16* __restrict__ WfTb)
{
    __shared__ float tile[64][65];   // 16,640 B
    const int b = blockIdx.x;
    const int t = threadIdx.x;

    if (b < PREP_X) {
        // x (xs|xq|zero-pad) -> fp8 e4m3 [4480][1024], 4 elems per thread
        const int e = (b * 256 + t) * 4;
        const int row = e >> 10;
        const int col = e & 1023;
        float4 v = make_float4(0.f, 0.f, 0.f, 0.f);
        if (row < NS)          v = *(const float4*)(xs + (size_t)row * D_IN + col);
        else if (row < M_ROWS) v = *(const float4*)(xq + (size_t)(row - NS) * D_IN + col);
        int p = __builtin_amdgcn_cvt_pk_fp8_f32(v.x, v.y, 0, false);
        p     = __builtin_amdgcn_cvt_pk_fp8_f32(v.z, v.w, p, true);
        const int ocol = col ^ (((row >> 1) & 1) << 3);     // half-swap on row bit1
        *(int*)(Xf8 + (size_t)row * D_IN + ocol) = p;
        return;
    }
    if (b < PREP_X + PREP_WS) {
        // W_share [1024][3200] -> Wsf8 [3200][1024] fp8, scaled x64, half-swapped
        const int tx = t & 63;
        const int ty = t >> 6;           // 0..3
        const int tb = b - PREP_X;
        const int n0 = (tb % 50) * 64;
        const int k0 = (tb / 50) * 64;
#pragma unroll
        for (int i = ty; i < 64; i += 4)
            tile[i][tx] = W_share[(size_t)(k0 + i) * D_FEAT + n0 + tx];
        __syncthreads();
#pragma unroll
        for (int i = ty; i < 64; i += 4) {
            const int p = __builtin_amdgcn_cvt_pk_fp8_f32(tile[tx][i] * WS_SCALE, 0.f,
                                                          0, false);
            const int n = n0 + i;
            const int k = (k0 + tx) ^ (((n >> 1) & 1) << 3); // half-swap on row bit1
            Wsf8[(size_t)n * D_IN + k] = (unsigned char)(p & 0xff);
        }
        return;
    }
    // W_fine dual-layout conversion: one 64x64 tile per block
    {
        const int tb = b - (PREP_X + PREP_WS);
        const int tx = t & 63;
        const int ty = t >> 6;           // 0..3
        const int n0 = (tb % 50) * 64;
        const int k0 = (tb / 50) * 64;
#pragma unroll
        for (int i = ty; i < 64; i += 4) {
            const float v = W_fine[(size_t)(k0 + i) * D_FEAT + n0 + tx];
            Wfb[(size_t)(k0 + i) * D_FEAT + n0 + tx] = (__bf16)v;   // 128B rows
            tile[i][tx] = v;
        }
        __syncthreads();
#pragma unroll
        for (int i = ty; i < 64; i += 4)
            WfTb[(size_t)(n0 + i) * D_FEAT + k0 + tx] = (__bf16)tile[tx][i];  // 128B
    }
}

// -------- fp8 MFMA GEMM, 128^2 tile, ONE barrier per 64B K-chunk ------------
// (unchanged from R12 -- measured best)
__global__ __launch_bounds__(256, 3) void gemm_fp8_128(const unsigned char* __restrict__ A,
                                                       const unsigned char* __restrict__ Bt,
                                                       const float* __restrict__ bias,
                                                       __bf16* __restrict__ out_bf)
{
    __shared__ __align__(16) unsigned char smem[49152];

    const int t    = threadIdx.x;
    const int lane = t & 63;
    const int w    = t >> 6;        // 0..3
    const int wm   = w >> 1;
    const int wn   = w & 1;

    const int bx = blockIdx.x % 25;
    const int by = blockIdx.x / 25;
    const int bm = by * 128;
    const int bn = bx * 128;

    const int q    = lane >> 4;     // k-octet group 0..3
    const int r16  = lane & 15;
    const int m3   = (r16 >> 1) & 7;
    const int off0 = (q ^ m3) * 8;  // half-0 swizzled byte offset; half-1: ^32

    const int rowA = (wm * 64 + r16) * 64;    // + mi*1024
    const int rowB = (wn * 64 + r16) * 64;    // + ni*1024

    const int srow  = t >> 2;
    const int sunit = 16 * ((t & 3) ^ ((srow >> 2) & 3));   // source-unit XOR

    const unsigned char* gA = A  + (size_t)(bm + srow) * D_IN + sunit;
    const unsigned char* gB = Bt + (size_t)(bn + srow) * D_IN + sunit;

    auto stage = [&](int uu, int slot) {
        const unsigned char* ga = gA + uu * 64;
        const unsigned char* gb = gB + uu * 64;
        unsigned char* l = smem + slot * 16384 + t * 16;
        __builtin_amdgcn_global_load_lds((gptr_t)ga,           (lptr_t)l,            16, 0, 0);
        __builtin_amdgcn_global_load_lds((gptr_t)(ga + 65536), (lptr_t)(l + 4096),   16, 0, 0);
        __builtin_amdgcn_global_load_lds((gptr_t)gb,           (lptr_t)(l + 8192),   16, 0, 0);
        __builtin_amdgcn_global_load_lds((gptr_t)(gb + 65536), (lptr_t)(l + 12288),  16, 0, 0);
    };

    floatx4 acc[4][4] = {};
    long av0[4], bv0[4], av1[4], bv1[4];

    auto ld16 = [&](const unsigned char* sa) {
#pragma unroll
        for (int mi = 0; mi < 4; ++mi)
            av0[mi] = *(const long*)(sa + rowA + mi * 1024 + off0);
#pragma unroll
        for (int ni = 0; ni < 4; ++ni)
            bv0[ni] = *(const long*)(sa + 8192 + rowB + ni * 1024 + off0);
#pragma unroll
        for (int mi = 0; mi < 4; ++mi)
            av1[mi] = *(const long*)(sa + rowA + mi * 1024 + (off0 ^ 32));
#pragma unroll
        for (int ni = 0; ni < 4; ++ni)
            bv1[ni] = *(const long*)(sa + 8192 + rowB + ni * 1024 + (off0 ^ 32));
    };
    auto mfma32 = [&]() {
        __builtin_amdgcn_s_setprio(1);
#pragma unroll
        for (int mi = 0; mi < 4; ++mi)
#pragma unroll
            for (int ni = 0; ni < 4; ++ni)
                acc[mi][ni] = __builtin_amdgcn_mfma_f32_16x16x32_fp8_fp8(
                    av0[mi], bv0[ni], acc[mi][ni], 0, 0, 0);
#pragma unroll
        for (int mi = 0; mi < 4; ++mi)
#pragma unroll
            for (int ni = 0; ni < 4; ++ni)
                acc[mi][ni] = __builtin_amdgcn_mfma_f32_16x16x32_fp8_fp8(
                    av1[mi], bv1[ni], acc[mi][ni], 0, 0, 0);
        __builtin_amdgcn_s_setprio(0);
    };

    stage(0, 0);
    stage(1, 1);

    for (int u = 0; u < 14; ++u) {
        const unsigned char* sa = smem + (u % 3) * 16384;
        asm volatile("s_waitcnt vmcnt(4)" ::: "memory");   // chunk u landed
        __builtin_amdgcn_s_barrier();
        ld16(sa);
        stage(u + 2, (u + 2) % 3);
        asm volatile("s_waitcnt lgkmcnt(0)" ::: "memory");
        mfma32();
    }
    {   // u = 14
        const unsigned char* sa = smem + (14 % 3) * 16384;
        asm volatile("s_waitcnt vmcnt(4)" ::: "memory");
        __builtin_amdgcn_s_barrier();
        ld16(sa);
        asm volatile("s_waitcnt lgkmcnt(0)" ::: "memory");
        mfma32();
    }
    {   // u = 15: drain
        const unsigned char* sa = smem + (15 % 3) * 16384;
        asm volatile("s_waitcnt vmcnt(0)" ::: "memory");
        __builtin_amdgcn_s_barrier();
        ld16(sa);
        asm volatile("s_waitcnt lgkmcnt(0)" ::: "memory");
        mfma32();
    }

    __syncthreads();                 // all frag reads done before overwrite
    float bcol[4];
#pragma unroll
    for (int ni = 0; ni < 4; ++ni) bcol[ni] = bias[bn + wn * 64 + ni * 16 + r16];
    const int ebase = (wm * 64 + q * 4) * 256 + wn * 128 + r16 * 2;
#pragma unroll
    for (int mi = 0; mi < 4; ++mi)
#pragma unroll
        for (int ni = 0; ni < 4; ++ni) {
            const int cb2 = (ni ^ q) << 5;
#pragma unroll
            for (int reg = 0; reg < 4; ++reg) {
                float v = acc[mi][ni][reg] * WS_INVSCALE + bcol[ni];
                v = fmaxf(v, 0.f);
                *(__bf16*)(smem + ebase + mi * 4096 + reg * 256 + cb2) = (__bf16)v;
            }
        }
    __syncthreads();
#pragma unroll
    for (int ps = 0; ps < 8; ++ps) {
        const int idx  = ps * 256 + t;
        const int row  = idx >> 4;           // 0..127
        const int grow = bm + row;
        if (grow < M_ROWS) {
            const int lb = row * 256 + (((idx & 15) << 4) ^ (((row >> 2) & 3) << 5));
            const int4 d = *(const int4*)(smem + lb);
            *(int4*)((char*)out_bf + ((size_t)grow * D_FEAT + bn + (idx & 15) * 8) * 2) = d;
        }
    }
}

// ------------- bf16 MFMA GEMM, rectangular tiles (R13) ----------------------
// <MI=4,NI=2>: 64M x 128N tile (zp, gt). <MI=2,NI=4>: 128M x 64N tile (cr).
// Counted-vmcnt 3-slot pipeline (R12): BK=32 chunks, slot = (RA+RB)*64 =
// 12,288 B, 3 slots = 36,864 B LDS. 3 gloads/chunk (192 rows), vmcnt(3).
// Accumulation per retained acc element: identical ascending-k order ->
// bit-identical outputs. Optional fusion: attUpool != null -> last grid block
// computes the att softmax weight vector (fence-free).
template<int MI, int NI>
__global__ __launch_bounds__(256) void gemm_bf16_t(const __bf16* __restrict__ A,
                                                   const __bf16* __restrict__ Bt,
                                                   float* __restrict__ out_f32,
                                                   int N, int strideK, int kIters,
                                                   int Mout, int sliceStride,
                                                   int nbx, int nby,
                                                   const float* __restrict__ attUpool,
                                                   const float* __restrict__ W_att,
                                                   const float* __restrict__ b_att,
                                                   float* __restrict__ wvec)
{
    constexpr int RA   = (MI == 4) ? 64 : 128;   // A-tile rows staged
    constexpr int RB   = (NI == 4) ? 64 : 128;   // B-tile rows staged
    constexpr int SLOT = (RA + RB) * 64;         // 12,288 B

    __shared__ __align__(16) char smem[3 * SLOT];   // 36,864 B
    const int t = threadIdx.x;

    if (attUpool != nullptr && blockIdx.x == gridDim.x - 1) {
        // ---- fused att block: pooled mean -> matvec (W_att via 16KB LDS
        // ---- quarters) -> softmax -> wvec[3200]. k-order 0..127 preserved.
        float* sW   = (float*)smem;                    // [32][128] quarter
        float* s_pm = (float*)(smem + 16384);
        float* s_at = (float*)(smem + 16384 + 512);
        float* s_dg = (float*)(smem + 16384 + 1024);
        if (t < C_CH) {
            float a = 0.f;
            for (int p = 0; p < N_CLASS; ++p) a += attUpool[(size_t)p * C_CH + t];
            s_pm[t] = a * (1.0f / (N_CLASS * 25));
        }
        __syncthreads();
        float acc = (t < C_CH) ? b_att[t] : 0.f;
#pragma unroll
        for (int qtr = 0; qtr < 4; ++qtr) {
            const float4* src = (const float4*)(W_att + qtr * 32 * C_CH);
            float4* dst = (float4*)sW;
#pragma unroll
            for (int i = 0; i < 4; ++i) dst[i * 256 + t] = src[i * 256 + t];
            __syncthreads();
            if (t < C_CH) {
#pragma unroll
                for (int k = 0; k < 32; ++k)
                    acc += s_pm[qtr * 32 + k] * sW[k * C_CH + t];
            }
            __syncthreads();
        }
        if (t < C_CH) s_at[t] = acc;
        __syncthreads();
        if (t < C_CH) {
            float m = -INFINITY;
            for (int k = 0; k < C_CH; ++k) m = fmaxf(m, s_at[k]);
            float s = 0.f;
            for (int k = 0; k < C_CH; ++k) s += expf(s_at[k] - m);
            s_dg[t] = expf(acc - m) / s * (float)C_CH;
        }
        __syncthreads();
        for (int j = t; j < D_FEAT; j += 256) wvec[j] = s_dg[j / 25];
        return;
    }

    int bx, by, ks;
    {
        const int nbxy = nbx * nby;
        ks = blockIdx.x / nbxy;
        const int b = blockIdx.x - ks * nbxy;
        bx = b % nbx;
        by = b / nbx;
    }

    const int lane = t & 63;
    const int w    = t >> 6;
    const int bm   = by * RA;       // 64-row tiles for MI=4; 128-row for MI=2
    const int bn   = bx * RB;

    const int q    = lane >> 4;
    const int r16  = lane & 15;
    const int sw   = (r16 >> 1) & 3;
    const int cA   = (q ^ sw) * 8;

    const int sglob8 = (((t & 3) ^ ((t >> 3) & 3))) * 8;

    const int kBase = ks * kIters * 32;
    floatx4 acc[MI][NI] = {};

    // stage chunk ki: 3 gloads/thread over 192 concat rows (A then B)
    auto stageb = [&](int ki, int slot) {
        const int k0 = kBase + ki * 32;
        char* base = smem + slot * SLOT;
#pragma unroll
        for (int g = 0; g < 3; ++g) {
            const int rr = g * 64 + (t >> 2);
            const __bf16* gp;
            if (g * 64 < RA)
                gp = A + (size_t)(bm + rr) * strideK + k0 + sglob8;
            else
                gp = Bt + (size_t)(bn + (rr - RA)) * strideK + k0 + sglob8;
            char* l = base + g * 4096 + t * 16;
            __builtin_amdgcn_global_load_lds((gptr_t)gp, (lptr_t)l, 16, 0, 0);
        }
    };

    bf16x8 av[MI], bv[NI];
    auto ldfrags = [&](const char* base) {
        const __bf16* sA = (const __bf16*)base;
        const __bf16* sB = (const __bf16*)(base + RA * 64);
        const int arb = (MI == 2) ? w * 32 : 0;
        const int brb = (NI == 2) ? w * 32 : 0;
#pragma unroll
        for (int mi = 0; mi < MI; ++mi)
            av[mi] = *(const bf16x8*)(sA + ((arb + mi * 16 + r16) * 32 + cA));
#pragma unroll
        for (int ni = 0; ni < NI; ++ni)
            bv[ni] = *(const bf16x8*)(sB + ((brb + ni * 16 + r16) * 32 + cA));
    };
    auto mfmaT = [&]() {
#pragma unroll
        for (int mi = 0; mi < MI; ++mi)
#pragma unroll
            for (int ni = 0; ni < NI; ++ni)
                acc[mi][ni] = __builtin_amdgcn_mfma_f32_16x16x32_bf16(
                    av[mi], bv[ni], acc[mi][ni], 0, 0, 0);
    };

    // prologue: chunks 0,1 in flight (6 gloads/thread)
    stageb(0, 0);
    stageb(1, 1);

    for (int u = 0; u < kIters; ++u) {
        const char* base = smem + (u % 3) * SLOT;
        if (u + 1 < kIters)
            asm volatile("s_waitcnt vmcnt(3)" ::: "memory");  // chunk u landed
        else
            asm volatile("s_waitcnt vmcnt(0)" ::: "memory");  // last chunk
        __builtin_amdgcn_s_barrier();
        ldfrags(base);
        if (u + 2 < kIters) stageb(u + 2, (u + 2) % 3);
        asm volatile("s_waitcnt lgkmcnt(0)" ::: "memory");
        mfmaT();
    }

    const int rb0 = bm + ((MI == 2) ? w * 32 : 0);
    const int cb0 = bn + ((NI == 2) ? w * 32 : 0);
#pragma unroll
    for (int ni = 0; ni < NI; ++ni) {
        const int col = cb0 + ni * 16 + r16;
#pragma unroll
        for (int mi = 0; mi < MI; ++mi) {
#pragma unroll
            for (int reg = 0; reg < 4; ++reg) {
                const int row = rb0 + mi * 16 + q * 4 + reg;
                if (row < Mout)
                    out_f32[(size_t)ks * sliceStride + (size_t)row * N + col] =
                        acc[mi][ni][reg];
            }
        }
    }
}

// ---- ut: support means + channel pools (64 blocks; W_fine conversion now
// ---- lives in prep)
__global__ __launch_bounds__(256) void ut_kernel(const __bf16* __restrict__ z_share,
                                                 __bf16* __restrict__ u,
                                                 float* __restrict__ upool)
{
    __shared__ float srow_[D_FEAT];   // 12.8 KB
    const int p = blockIdx.x;        // 0..63
    const int t = threadIdx.x;
    const __bf16* base = z_share + (size_t)(p * N_SUPPORT) * D_FEAT;
    for (int k = t; k < D_FEAT; k += 256) {
        float s = 0.f;
#pragma unroll
        for (int ss = 0; ss < N_SUPPORT; ++ss) s += (float)base[(size_t)ss * D_FEAT + k];
        s *= (1.0f / N_SUPPORT);
        u[(size_t)p * D_FEAT + k] = (__bf16)s;
        srow_[k] = s;
    }
    __syncthreads();
    if (t < C_CH) {
        float pool = 0.f;
#pragma unroll
        for (int win = 0; win < 25; ++win) pool += srow_[t * 25 + win];
        upool[(size_t)p * C_CH + t] = pool;
    }
}

// ---------------- y = w*(sum zp_part + bf) bf16 [64][3200]; p2; c -------------------
__global__ __launch_bounds__(256) void y_kernel(const float* __restrict__ zp_part,
                                                const float* __restrict__ wv,
                                                const float* __restrict__ bf,
                                                __bf16* __restrict__ y,
                                                float* __restrict__ p2,
                                                float* __restrict__ cvec)
{
    __shared__ float s_red2[8];
    const int p = blockIdx.x;        // 0..63
    const int t = threadIdx.x;
    float s2 = 0.f, sc = 0.f;
    for (int j = t; j < D_FEAT; j += 256) {
        float zpf = bf[j];
#pragma unroll
        for (int ss = 0; ss < NKS; ++ss)
            zpf += zp_part[(size_t)ss * ZP_SLICE + (size_t)p * D_FEAT + j];
        const float wj = wv[j];
        y[(size_t)p * D_FEAT + j] = (__bf16)(wj * zpf);
        s2 += wj * zpf * zpf;
        sc += bf[j] * wj * zpf;
    }
    s2 = waveReduceSum(s2);
    sc = waveReduceSum(sc);
    const int lane = t & 63, wid = t >> 6;
    if (lane == 0) { s_red2[wid] = s2; s_red2[4 + wid] = sc; }
    __syncthreads();
    if (t == 0) {
        p2[p]   = s_red2[0] + s_red2[1] + s_red2[2] + s_red2[3];
        cvec[p] = s_red2[4] + s_red2[5] + s_red2[6] + s_red2[7];
    }
}

// ---------------- Gt[p][k] bf16 = sum of NKS fp32 slices [64][3200] -----------------
__global__ __launch_bounds__(256) void gtsum_kernel(const float* __restrict__ gp,
                                                    __bf16* __restrict__ Gt)
{
    const int i4 = blockIdx.x * 256 + threadIdx.x;     // over 204800/4
    if (i4 >= GT_SLICE / 4) return;
    float4 s = make_float4(0.f, 0.f, 0.f, 0.f);
#pragma unroll
    for (int ss = 0; ss < NKS; ++ss) {
        const float4 v = *(const float4*)(gp + (size_t)ss * GT_SLICE + i4 * 4);
        s.x += v.x; s.y += v.y; s.z += v.z; s.w += v.w;
    }
    bf16x4 o = { (__bf16)s.x, (__bf16)s.y, (__bf16)s.z, (__bf16)s.w };
    *(bf16x4*)(Gt + (size_t)i4 * 4) = o;
}

// ---------------- softmax/loss: one wave per query, block partials (no atomics) -----
__global__ __launch_bounds__(256) void loss_kernel(const float* __restrict__ cross_part,
                                                   const float* __restrict__ p2,
                                                   const float* __restrict__ cvec,
                                                   float* __restrict__ lpart)
{
    __shared__ float s_l[4], s_a[4];
    const int t = threadIdx.x;
    const int lane = t & 63, wid = t >> 6;
    const int i = blockIdx.x * 4 + wid;       // query 0..4095
    float cr = 0.f;
#pragma unroll
    for (int ss = 0; ss < NKS; ++ss)
        cr += cross_part[(size_t)ss * CR_SLICE + (size_t)i * 128 + lane];
    const float neg = 2.0f * (cr + cvec[lane]) - p2[lane];   // -(dist) + const/row
    float m = neg;
    for (int off = 32; off > 0; off >>= 1) m = fmaxf(m, __shfl_xor(m, off, 64));
    float e = expf(neg - m);
    float ssum = e;
    for (int off = 32; off > 0; off >>= 1) ssum += __shfl_xor(ssum, off, 64);
    const float lse = m + logf(ssum);
    const int tcls = i >> 6;
    const float negt = __shfl(neg, tcls, 64);
    float v = -neg; int bi = lane;            // argmin dist == argmax neg, first on tie
    for (int off = 32; off > 0; off >>= 1) {
        const float ov = __shfl_xor(v, off, 64);
        const int   oi = __shfl_xor(bi, off, 64);
        if (ov < v || (ov == v && oi < bi)) { v = ov; bi = oi; }
    }
    if (lane == 0) { s_l[wid] = lse - negt; s_a[wid] = (bi == tcls) ? 1.0f : 0.0f; }
    __syncthreads();
    if (t == 0) {
        lpart[blockIdx.x]             = s_l[0] + s_l[1] + s_l[2] + s_l[3];
        lpart[LOSS_BLKS + blockIdx.x] = s_a[0] + s_a[1] + s_a[2] + s_a[3];
    }
}

__global__ __launch_bounds__(256) void writeout_kernel(const float* __restrict__ lpart,
                                                       float* __restrict__ out)
{
    __shared__ float s_red2[8];
    const int t = threadIdx.x;
    float l = 0.f, a = 0.f;
    for (int k = t; k < LOSS_BLKS; k += 256) {
        l += lpart[k];
        a += lpart[LOSS_BLKS + k];
    }
    l = waveReduceSum(l);
    a = waveReduceSum(a);
    const int lane = t & 63, wid = t >> 6;
    if (lane == 0) { s_red2[wid] = l; s_red2[4 + wid] = a; }
    __syncthreads();
    if (t == 0) {
        out[0] = (s_red2[0] + s_red2[1] + s_red2[2] + s_red2[3]) * (1.0f / NQ);
        out[1] = (s_red2[4] + s_red2[5] + s_red2[6] + s_red2[7]) * (1.0f / NQ);
    }
}

extern "C" void kernel_launch(void* const* d_in, const int* in_sizes, int n_in,
                              void* d_out, int out_size, void* d_ws, size_t ws_size,
                              hipStream_t stream)
{
    const float* xs      = (const float*)d_in[0];
    const float* xq      = (const float*)d_in[1];
    const float* W_share = (const float*)d_in[2];
    const float* b_share = (const float*)d_in[3];
    const float* W_att   = (const float*)d_in[4];
    const float* b_att   = (const float*)d_in[5];
    const float* W_fine  = (const float*)d_in[6];
    const float* b_fine  = (const float*)d_in[7];
    float* out = (float*)d_out;

    char* ws = (char*)d_ws;
    unsigned char* Xf8  = (unsigned char*)(ws + WS_XF8);
    unsigned char* Wsf8 = (unsigned char*)(ws + WS_WSF8);
    __bf16* Zsb     = (__bf16*)(ws + WS_ZSB);
    __bf16* Wfb     = (__bf16*)(ws + WS_WFB);
    __bf16* WfTb    = (__bf16*)(ws + WS_WFTB);
    float*  arena   = (float*) (ws + WS_ARENA);
    float*  zp_part = arena;                  // 10*204800*4 =  8,192,000
    float*  gt_part = arena;                  // 10*204800*4 =  8,192,000
    float*  cr_part = arena;                  // 10*524288*4 = 20,971,520
    __bf16* ub      = (__bf16*)(ws + WS_UB);
    __bf16* yb      = (__bf16*)(ws + WS_YB);
    __bf16* Gt      = (__bf16*)(ws + WS_GT);
    float*  wv      = (float*) (ws + WS_WV);
    float*  p2v     = (float*) (ws + WS_P2);
    float*  cvec    = (float*) (ws + WS_CVEC);
    float*  lpart   = (float*) (ws + WS_LPART);
    float*  upool   = (float*) (ws + WS_UPOOL);  // own slot (att overlaps zp)

    // prep: x->fp8 | W_share^T->fp8 x64 | W_fine -> Wfb/WfTb bf16 (all 64x64)
    prep_kernel<<<PREP_X + PREP_WS + CONV64, 256, 0, stream>>>(
        xs, xq, W_share, W_fine, Xf8, Wsf8, Wfb, WfTb);

    // z_share = relu((x @ W_share)*1/64 + b_share) [4416][3200] bf16
    gemm_fp8_128<<<GEMM8_BLKS, 256, 0, stream>>>(Xf8, Wsf8, b_share, Zsb);

    // support means + channel pools
    ut_kernel<<<64, 256, 0, stream>>>(Zsb, ub, upool);

    // zp_part[ks][p][j] = partial u @ Wf  (64M x 128N tiles)  M=64, N=3200
    // + fused att tail block (grid 251): upool -> matvec -> softmax -> wv
    gemm_bf16_t<4, 2><<<25 * NKS + 1, 256, 0, stream>>>(
        ub, WfTb, zp_part,
        D_FEAT, D_FEAT, 10, N_CLASS, ZP_SLICE, 25, 1,
        upool, W_att, b_att, wv);

    // y = w*(zp+b_fine), p2, c   (rows 0..63 only)
    y_kernel<<<64, 256, 0, stream>>>(zp_part, wv, b_fine, yb, p2v, cvec);

    // gt_part[ks][p][k] = partial y @ Wf^T  (64M x 128N)  M=64
    gemm_bf16_t<4, 2><<<25 * NKS, 256, 0, stream>>>(
        yb, Wfb, gt_part,
        D_FEAT, D_FEAT, 10, N_CLASS, GT_SLICE, 25, 1,
        nullptr, nullptr, nullptr, nullptr);

    // Gt bf16 [64][3200] = sum of slices
    gtsum_kernel<<<(GT_SLICE / 4 + 255) / 256, 256, 0, stream>>>(gt_part, Gt);

    // cr_part[ks][i][p] = partial zs_q @ Gt^T  (128M x 64N)  64 real cols
    gemm_bf16_t<2, 4><<<32 * NKS, 256, 0, stream>>>(
        Zsb + (size_t)NS * D_FEAT, Gt, cr_part,
        128, D_FEAT, 10, NQ, CR_SLICE, 1, 32,
        nullptr, nullptr, nullptr, nullptr);

    // per-query log-softmax + loss/acc -> block partials (no atomics)
    loss_kernel<<<LOSS_BLKS, 256, 0, stream>>>(cr_part, p2v, cvec, lpart);

    // final reduction ends with PLAIN STORES to d_out (R10 lesson)
    writeout_kernel<<<1, 256, 0, stream>>>(lpart, out);
}